// Round 4
// baseline (272.388 us; speedup 1.0000x reference)
//
#include <hip/hip_runtime.h>

#define NN 512
#define SCALE 0.35355339059327373f  /* dk^-0.5, dk=8 */

// ---------------- K1: QKV projection ----------------
__global__ __launch_bounds__(64) void qkv_proj(const float* __restrict__ nin,
                                               const float* __restrict__ Wqkv,
                                               float* __restrict__ qkv) {
    const int r = blockIdx.x;   // b*512+n
    const int j = threadIdx.x;  // 0..63
    const float* nr = nin + (size_t)r * 64;
    float a0 = 0.f, a1 = 0.f, a2 = 0.f;
#pragma unroll
    for (int d = 0; d < 64; ++d) {
        const float nv = nr[d];                 // block-uniform -> s_load
        const float* wr = Wqkv + d * 192;
        a0 = fmaf(nv, wr[j], a0);
        a1 = fmaf(nv, wr[64 + j], a1);
        a2 = fmaf(nv, wr[128 + j], a2);
    }
    float* o = qkv + (size_t)r * 192;
    o[j] = a0; o[64 + j] = a1; o[128 + j] = a2;
}

// ---------------- K2: scores + softmax + PV + n_out ----------------
// block = (b,n) row, 256 threads. Streaming phase: lane owns edge m (2 rows),
// full e-row preloaded into 16 float4 regs for deep VMEM pipelining.
// _E row (512*8 f32 = 16 KB) stashed at the head of this row's e_out region.
__global__ __launch_bounds__(256, 4) void edge_score_pv(
    const float* __restrict__ e,
    const float* __restrict__ qkv,
    const float* __restrict__ We,   // (64,8)
    const float* __restrict__ Wg,   // (64,8)
    const float* __restrict__ On,   // (64,64)
    float* __restrict__ n_out,      // (B,N,64)
    float* __restrict__ e_out)      // (B,N,N,64) — row head reused as _E stash
{
    __shared__ float Es[NN * 8];    // 16 KB: _E then (in-place) P = exp(_E - mx)
    __shared__ float red[256];      // reused: pmax -> psum -> vpart -> npart
    __shared__ float gred[4][8];
    __shared__ float vfin[64];
    __shared__ float mx[8], invden[8], centr[8];

    const int t = threadIdx.x;
    const int w = t >> 6;
    const int l = t & 63;
    const int bn = blockIdx.x;
    const int b = bn >> 9;
    const float* Q = qkv + (size_t)bn * 192;          // block-uniform -> s_load
    const float* eb = e + (size_t)bn * 512 * 64;
    float* Erow = e_out + (size_t)bn * 32768;

    float gs[8];
#pragma unroll
    for (int j = 0; j < 8; ++j) gs[j] = 0.f;

#pragma unroll
    for (int half = 0; half < 2; ++half) {
        const int m = t + half * 256;
        const float4* e4 = reinterpret_cast<const float4*>(eb + (size_t)m * 64);
        const float4* k4 = reinterpret_cast<const float4*>(qkv + (size_t)(b * NN + m) * 192 + 64);
        float4 er[16];
#pragma unroll
        for (int u = 0; u < 16; ++u) er[u] = e4[u];   // 16 loads issued up front
        float ee[8], gg[8], ar[8];
#pragma unroll
        for (int j = 0; j < 8; ++j) { ee[j] = 0.f; gg[j] = 0.f; ar[j] = 0.f; }
#pragma unroll
        for (int u = 0; u < 16; ++u) {
            const float4 kv = k4[u];
            const float ec[4] = {er[u].x, er[u].y, er[u].z, er[u].w};
            const float kc[4] = {kv.x, kv.y, kv.z, kv.w};
            const float* wE = We + u * 32;            // uniform -> s_load
            const float* wG = Wg + u * 32;
            const float* qp = Q + u * 4;
#pragma unroll
            for (int c = 0; c < 4; ++c) {
#pragma unroll
                for (int j = 0; j < 8; ++j) {
                    ee[j] = fmaf(ec[c], wE[c * 8 + j], ee[j]);
                    gg[j] = fmaf(ec[c], wG[c * 8 + j], gg[j]);
                }
                ar[u >> 1] = fmaf(kc[c], qp[c], ar[u >> 1]);
            }
        }
        float Eh[8];
#pragma unroll
        for (int j = 0; j < 8; ++j) {
            const float a = fminf(fmaxf(ar[j] * SCALE, -5.f), 5.f);
            Eh[j] = a + ee[j];
            gs[j] += 1.f / (1.f + __expf(-gg[j]));
        }
        float4* sd = reinterpret_cast<float4*>(Erow + (size_t)m * 8);
        const float4 h0 = make_float4(Eh[0], Eh[1], Eh[2], Eh[3]);
        const float4 h1 = make_float4(Eh[4], Eh[5], Eh[6], Eh[7]);
        sd[0] = h0; sd[1] = h1;                       // global stash for K3
        float4* ld = reinterpret_cast<float4*>(Es + (size_t)m * 8);
        ld[0] = h0; ld[1] = h1;                       // LDS copy for this block
    }
    // wave-reduce gate sums
#pragma unroll
    for (int off = 1; off < 64; off <<= 1)
#pragma unroll
        for (int j = 0; j < 8; ++j) gs[j] += __shfl_xor(gs[j], off, 64);
    if (l == 0)
#pragma unroll
        for (int j = 0; j < 8; ++j) gred[w][j] = gs[j];
    __syncthreads();

    const int h8 = t & 7, g32 = t >> 3;
    {   // per-head partial max
        float vm = -1e30f;
#pragma unroll 4
        for (int i = 0; i < 16; ++i) vm = fmaxf(vm, Es[(g32 + 32 * i) * 8 + h8]);
        red[g32 * 8 + h8] = vm;
    }
    __syncthreads();
    if (t < 8) {
        float m_ = red[t];
        for (int g = 1; g < 32; ++g) m_ = fmaxf(m_, red[g * 8 + t]);
        mx[t] = m_;
        centr[t] = log1pf(gred[0][t] + gred[1][t] + gred[2][t] + gred[3][t]);
    }
    __syncthreads();
    {   // exp + partial sum; overwrite Es with P in place (each elem owned by 1 thread)
        const float mh = mx[h8];
        float ss = 0.f;
#pragma unroll 4
        for (int i = 0; i < 16; ++i) {
            const int idx = (g32 + 32 * i) * 8 + h8;
            const float p = __expf(Es[idx] - mh);
            Es[idx] = p;
            ss += p;
        }
        red[g32 * 8 + h8] = ss;
    }
    __syncthreads();
    if (t < 8) {
        float s_ = 0.f;
        for (int g = 0; g < 32; ++g) s_ += red[g * 8 + t];
        invden[t] = 1.f / s_;
    }
    __syncthreads();
    // PV: thread=(k,h,w-quarter); V rows L2-hot
    {
        const int k = t & 7, hh = (t >> 3) & 7;
        const float* vb = qkv + (size_t)(b * NN) * 192 + 128 + hh * 8 + k;
        float acc = 0.f;
#pragma unroll 4
        for (int i = 0; i < 128; ++i) {
            const int m = w * 128 + i;
            acc = fmaf(Es[m * 8 + hh], vb[(size_t)m * 192], acc);
        }
        red[t] = acc;
    }
    __syncthreads();
    if (t < 64) {
        const int hh = t >> 3;
        vfin[t] = (red[t] + red[64 + t] + red[128 + t] + red[192 + t]) * invden[hh] * centr[hh];
    }
    __syncthreads();
    // n_out = vfin @ On
    {
        float acc = 0.f;
#pragma unroll
        for (int i = w * 16; i < w * 16 + 16; ++i)
            acc = fmaf(vfin[i], On[i * 64 + l], acc);
        red[t] = acc;
    }
    __syncthreads();
    if (t < 64) {
        n_out[(size_t)bn * 64 + t] = red[t] + red[64 + t] + red[128 + t] + red[192 + t];
    }
}

// ---------------- K3: e_out = _E @ Oe (pure streaming) ----------------
__global__ __launch_bounds__(256) void edge_out_stream(
    const float* __restrict__ Oe,   // (8,64)
    float* __restrict__ e_out)      // (B,N,N,64); row head holds the _E stash
{
    __shared__ float Es[NN * 8];    // 16 KB
    const int t = threadIdx.x;
    const int w = t >> 6;
    const int l = t & 63;
    const int bn = blockIdx.x;
    float* erow = e_out + (size_t)bn * 32768;

    {   // stash -> LDS
        const float4* src = reinterpret_cast<const float4*>(erow);
        float4* dst = reinterpret_cast<float4*>(Es);
#pragma unroll
        for (int i = 0; i < 4; ++i) dst[t + 256 * i] = src[t + 256 * i];
    }
    __syncthreads();

    const int j4 = l & 15, mr = l >> 4;
    float oc[8][4];
#pragma unroll
    for (int h = 0; h < 8; ++h) {
        const float4 v = reinterpret_cast<const float4*>(Oe + h * 64 + j4 * 4)[0];
        oc[h][0] = v.x; oc[h][1] = v.y; oc[h][2] = v.z; oc[h][3] = v.w;
    }
#pragma unroll 4
    for (int p = 0; p < 32; ++p) {
        const int m = w * 128 + p * 4 + mr;
        const float* er = Es + m * 8;
        const float4 ra = reinterpret_cast<const float4*>(er)[0];
        const float4 rb = reinterpret_cast<const float4*>(er)[1];
        float o0 = ra.x * oc[0][0], o1 = ra.x * oc[0][1], o2 = ra.x * oc[0][2], o3 = ra.x * oc[0][3];
        o0 = fmaf(ra.y, oc[1][0], o0); o1 = fmaf(ra.y, oc[1][1], o1); o2 = fmaf(ra.y, oc[1][2], o2); o3 = fmaf(ra.y, oc[1][3], o3);
        o0 = fmaf(ra.z, oc[2][0], o0); o1 = fmaf(ra.z, oc[2][1], o1); o2 = fmaf(ra.z, oc[2][2], o2); o3 = fmaf(ra.z, oc[2][3], o3);
        o0 = fmaf(ra.w, oc[3][0], o0); o1 = fmaf(ra.w, oc[3][1], o1); o2 = fmaf(ra.w, oc[3][2], o2); o3 = fmaf(ra.w, oc[3][3], o3);
        o0 = fmaf(rb.x, oc[4][0], o0); o1 = fmaf(rb.x, oc[4][1], o1); o2 = fmaf(rb.x, oc[4][2], o2); o3 = fmaf(rb.x, oc[4][3], o3);
        o0 = fmaf(rb.y, oc[5][0], o0); o1 = fmaf(rb.y, oc[5][1], o1); o2 = fmaf(rb.y, oc[5][2], o2); o3 = fmaf(rb.y, oc[5][3], o3);
        o0 = fmaf(rb.z, oc[6][0], o0); o1 = fmaf(rb.z, oc[6][1], o1); o2 = fmaf(rb.z, oc[6][2], o2); o3 = fmaf(rb.z, oc[6][3], o3);
        o0 = fmaf(rb.w, oc[7][0], o0); o1 = fmaf(rb.w, oc[7][1], o1); o2 = fmaf(rb.w, oc[7][2], o2); o3 = fmaf(rb.w, oc[7][3], o3);
        reinterpret_cast<float4*>(erow + (size_t)m * 64 + j4 * 4)[0] = make_float4(o0, o1, o2, o3);
    }
}

extern "C" void kernel_launch(void* const* d_in, const int* in_sizes, int n_in,
                              void* d_out, int out_size, void* d_ws, size_t ws_size,
                              hipStream_t stream) {
    const float* n_in_p = (const float*)d_in[0];
    const float* e_p    = (const float*)d_in[1];
    const float* Wqkv   = (const float*)d_in[2];
    const float* On     = (const float*)d_in[3];
    const float* Wg     = (const float*)d_in[4];
    const float* We     = (const float*)d_in[5];
    const float* Oe     = (const float*)d_in[6];
    float* out = (float*)d_out;
    float* n_out = out;                              // 4*512*64
    float* e_out = out + (size_t)4 * 512 * 64;       // 4*512*512*64
    float* qkv = (float*)d_ws;                       // 4*512*192 floats

    hipLaunchKernelGGL(qkv_proj, dim3(4 * NN), dim3(64), 0, stream, n_in_p, Wqkv, qkv);
    hipLaunchKernelGGL(edge_score_pv, dim3(4 * NN), dim3(256), 0, stream,
                       e_p, qkv, We, Wg, On, n_out, e_out);
    hipLaunchKernelGGL(edge_out_stream, dim3(4 * NN), dim3(256), 0, stream,
                       Oe, e_out);
}

// Round 5
// 240.783 us; speedup vs baseline: 1.1313x; 1.1313x over previous
//
#include <hip/hip_runtime.h>

#define NN 512
#define SCALE 0.35355339059327373f  /* dk^-0.5, dk=8 */
#define SMAX 6.0f                   /* fixed softmax shift (exact; data-safe) */

// ---------------- K1: QKV projection ----------------
__global__ __launch_bounds__(64) void qkv_proj(const float* __restrict__ nin,
                                               const float* __restrict__ Wqkv,
                                               float* __restrict__ qkv) {
    const int r = blockIdx.x;   // b*512+n
    const int j = threadIdx.x;  // 0..63
    const float* nr = nin + (size_t)r * 64;
    float a0 = 0.f, a1 = 0.f, a2 = 0.f;
#pragma unroll
    for (int d = 0; d < 64; ++d) {
        const float nv = nr[d];                 // block-uniform -> s_load
        const float* wr = Wqkv + d * 192;
        a0 = fmaf(nv, wr[j], a0);
        a1 = fmaf(nv, wr[64 + j], a1);
        a2 = fmaf(nv, wr[128 + j], a2);
    }
    float* o = qkv + (size_t)r * 192;
    o[j] = a0; o[64 + j] = a1; o[128 + j] = a2;
}

// ---------------- K2: fully fused edge kernel ----------------
// block = (b,n) row, 256 threads / 4 waves. Streaming: quad (4 lanes) owns a
// row; per-instruction addresses are quad-contiguous 64B segments -> every
// memory request carries a full cache line.
__global__ __launch_bounds__(256, 4) void edge_all(
    const float* __restrict__ e,
    const float* __restrict__ qkv,
    const float* __restrict__ We,   // (64,8)
    const float* __restrict__ Wg,   // (64,8)
    const float* __restrict__ Oe,   // (8,64)
    const float* __restrict__ On,   // (64,64)
    float* __restrict__ n_out,      // (B,N,64)
    float* __restrict__ e_out)      // (B,N,N,64)
{
    __shared__ float Wl[2 * 64 * 12];   // We|Wg, rows padded to 12 floats (6 KB)
    __shared__ float Es[NN * 8];        // _E scores, f32 (16 KB)
    __shared__ float red[256];
    __shared__ float gred[4][8];
    __shared__ float vfin[64];
    __shared__ float invden[8], centr[8];

    const int t = threadIdx.x;
    const int w = t >> 6;
    const int l = t & 63;
    const int c = l & 3;        // quad lane
    const int rl = l >> 2;      // row-in-chunk 0..15
    const int bn = blockIdx.x;
    const int b = bn >> 9;

    // stage We/Wg into LDS (padded rows)
    for (int i = t; i < 512; i += 256) {
        Wl[(i >> 3) * 12 + (i & 7)] = We[i];
        Wl[768 + (i >> 3) * 12 + (i & 7)] = Wg[i];
    }
    // per-lane Q fragment: Qr[i][cc] = Q[i*16 + c*4 + cc]
    const float* Q = qkv + (size_t)bn * 192;
    float4 Qr[4];
#pragma unroll
    for (int i = 0; i < 4; ++i) Qr[i] = *reinterpret_cast<const float4*>(Q + i * 16 + c * 4);
    __syncthreads();

    const float* e_base = e + (size_t)bn * 32768;
    float gs[8];
#pragma unroll
    for (int j = 0; j < 8; ++j) gs[j] = 0.f;

#pragma unroll
    for (int ch = 0; ch < 8; ++ch) {
        const int row = w * 128 + ch * 16 + rl;   // this quad's m
        const float* er_ = e_base + row * 64;
        const float* kr_ = qkv + (size_t)(b * NN + row) * 192 + 64;
        float4 ev[4], kv[4];
#pragma unroll
        for (int i = 0; i < 4; ++i) {
            ev[i] = *reinterpret_cast<const float4*>(er_ + i * 16 + c * 4);
            kv[i] = *reinterpret_cast<const float4*>(kr_ + i * 16 + c * 4);
        }
        float ee[8], gg[8], arp[4];
#pragma unroll
        for (int j = 0; j < 8; ++j) { ee[j] = 0.f; gg[j] = 0.f; }
#pragma unroll
        for (int i = 0; i < 4; ++i) arp[i] = 0.f;
#pragma unroll
        for (int i = 0; i < 4; ++i) {
            const float evc[4] = {ev[i].x, ev[i].y, ev[i].z, ev[i].w};
            const float kvc[4] = {kv[i].x, kv[i].y, kv[i].z, kv[i].w};
            const float qvc[4] = {Qr[i].x, Qr[i].y, Qr[i].z, Qr[i].w};
#pragma unroll
            for (int cc = 0; cc < 4; ++cc) {
                const int d = i * 16 + c * 4 + cc;         // lane's d-index
                const float4 w0 = *reinterpret_cast<const float4*>(&Wl[d * 12]);
                const float4 w1 = *reinterpret_cast<const float4*>(&Wl[d * 12 + 4]);
                const float4 g0 = *reinterpret_cast<const float4*>(&Wl[768 + d * 12]);
                const float4 g1 = *reinterpret_cast<const float4*>(&Wl[768 + d * 12 + 4]);
                const float evv = evc[cc];
                ee[0] = fmaf(evv, w0.x, ee[0]); ee[1] = fmaf(evv, w0.y, ee[1]);
                ee[2] = fmaf(evv, w0.z, ee[2]); ee[3] = fmaf(evv, w0.w, ee[3]);
                ee[4] = fmaf(evv, w1.x, ee[4]); ee[5] = fmaf(evv, w1.y, ee[5]);
                ee[6] = fmaf(evv, w1.z, ee[6]); ee[7] = fmaf(evv, w1.w, ee[7]);
                gg[0] = fmaf(evv, g0.x, gg[0]); gg[1] = fmaf(evv, g0.y, gg[1]);
                gg[2] = fmaf(evv, g0.z, gg[2]); gg[3] = fmaf(evv, g0.w, gg[3]);
                gg[4] = fmaf(evv, g1.x, gg[4]); gg[5] = fmaf(evv, g1.y, gg[5]);
                gg[6] = fmaf(evv, g1.z, gg[6]); gg[7] = fmaf(evv, g1.w, gg[7]);
                arp[i] = fmaf(kvc[cc], qvc[cc], arp[i]);
            }
        }
        // quad butterfly: full sums for ee/gg; per-head sums for arp
#pragma unroll
        for (int j = 0; j < 8; ++j) {
            ee[j] += __shfl_xor(ee[j], 1, 64);
            gg[j] += __shfl_xor(gg[j], 1, 64);
        }
#pragma unroll
        for (int j = 0; j < 8; ++j) {
            ee[j] += __shfl_xor(ee[j], 2, 64);
            gg[j] += __shfl_xor(gg[j], 2, 64);
        }
        // arp: xor1 merges lanes covering same head; lane holds head 2i+(c>>1)
#pragma unroll
        for (int i = 0; i < 4; ++i) arp[i] += __shfl_xor(arp[i], 1, 64);
        float aro[4];
#pragma unroll
        for (int i = 0; i < 4; ++i) aro[i] = __shfl_xor(arp[i], 2, 64);
        const int podd = (c >> 1);   // 0: arp holds even heads; 1: odd heads
        float EE[8];
#pragma unroll
        for (int i = 0; i < 4; ++i) {
            const float a_own = fminf(fmaxf(arp[i] * SCALE, -5.f), 5.f);
            const float a_oth = fminf(fmaxf(aro[i] * SCALE, -5.f), 5.f);
            const float a_ev = (podd == 0) ? a_own : a_oth;
            const float a_od = (podd == 0) ? a_oth : a_own;
            EE[2 * i]     = a_ev + ee[2 * i];
            EE[2 * i + 1] = a_od + ee[2 * i + 1];
        }
#pragma unroll
        for (int j = 0; j < 8; ++j) gs[j] += 1.f / (1.f + __expf(-gg[j]));
        // lane c writes its head-pair (2c, 2c+1) of this row
        const float e0 = (c == 0) ? EE[0] : (c == 1) ? EE[2] : (c == 2) ? EE[4] : EE[6];
        const float e1 = (c == 0) ? EE[1] : (c == 1) ? EE[3] : (c == 2) ? EE[5] : EE[7];
        *reinterpret_cast<float2*>(&Es[row * 8 + c * 2]) = make_float2(e0, e1);
    }
    // gate sums: quad-duplicated 4x -> scale by 0.25 at write
#pragma unroll
    for (int off = 1; off < 64; off <<= 1)
#pragma unroll
        for (int j = 0; j < 8; ++j) gs[j] += __shfl_xor(gs[j], off, 64);
    if (l == 0)
#pragma unroll
        for (int j = 0; j < 8; ++j) gred[w][j] = gs[j] * 0.25f;
    __syncthreads();

    // ---- e_out = _E @ Oe first: big stores drain under later compute ----
    {
        const int j4 = l & 15, mr = l >> 4;
        float oc[8][4];
#pragma unroll
        for (int h = 0; h < 8; ++h) {
            const float4 v = reinterpret_cast<const float4*>(Oe + h * 64 + j4 * 4)[0];
            oc[h][0] = v.x; oc[h][1] = v.y; oc[h][2] = v.z; oc[h][3] = v.w;
        }
        float* eob = e_out + (size_t)bn * 32768;
#pragma unroll 2
        for (int p = 0; p < 32; ++p) {
            const int m = w * 128 + p * 4 + mr;
            const float* er = Es + m * 8;
            const float4 ra = reinterpret_cast<const float4*>(er)[0];
            const float4 rb = reinterpret_cast<const float4*>(er)[1];
            float o0 = ra.x * oc[0][0], o1 = ra.x * oc[0][1], o2 = ra.x * oc[0][2], o3 = ra.x * oc[0][3];
            o0 = fmaf(ra.y, oc[1][0], o0); o1 = fmaf(ra.y, oc[1][1], o1); o2 = fmaf(ra.y, oc[1][2], o2); o3 = fmaf(ra.y, oc[1][3], o3);
            o0 = fmaf(ra.z, oc[2][0], o0); o1 = fmaf(ra.z, oc[2][1], o1); o2 = fmaf(ra.z, oc[2][2], o2); o3 = fmaf(ra.z, oc[2][3], o3);
            o0 = fmaf(ra.w, oc[3][0], o0); o1 = fmaf(ra.w, oc[3][1], o1); o2 = fmaf(ra.w, oc[3][2], o2); o3 = fmaf(ra.w, oc[3][3], o3);
            o0 = fmaf(rb.x, oc[4][0], o0); o1 = fmaf(rb.x, oc[4][1], o1); o2 = fmaf(rb.x, oc[4][2], o2); o3 = fmaf(rb.x, oc[4][3], o3);
            o0 = fmaf(rb.y, oc[5][0], o0); o1 = fmaf(rb.y, oc[5][1], o1); o2 = fmaf(rb.y, oc[5][2], o2); o3 = fmaf(rb.y, oc[5][3], o3);
            o0 = fmaf(rb.z, oc[6][0], o0); o1 = fmaf(rb.z, oc[6][1], o1); o2 = fmaf(rb.z, oc[6][2], o2); o3 = fmaf(rb.z, oc[6][3], o3);
            o0 = fmaf(rb.w, oc[7][0], o0); o1 = fmaf(rb.w, oc[7][1], o1); o2 = fmaf(rb.w, oc[7][2], o2); o3 = fmaf(rb.w, oc[7][3], o3);
            reinterpret_cast<float4*>(eob + (size_t)m * 64 + j4 * 4)[0] = make_float4(o0, o1, o2, o3);
        }
    }
    // ---- softmax denominators (fixed shift SMAX; no max pass) ----
    const int h8 = t & 7, g32 = t >> 3;
    {
        float ss = 0.f;
#pragma unroll 4
        for (int i = 0; i < 16; ++i) ss += __expf(Es[(g32 + 32 * i) * 8 + h8] - SMAX);
        red[g32 * 8 + h8] = ss;
    }
    __syncthreads();
    if (t < 8) {
        float s_ = 0.f;
        for (int g = 0; g < 32; ++g) s_ += red[g * 8 + t];
        invden[t] = 1.f / s_;
        centr[t] = log1pf(gred[0][t] + gred[1][t] + gred[2][t] + gred[3][t]);
    }
    __syncthreads();
    // ---- PV: thread=(k,h); wave = m-quarter; V rows L2-hot ----
    {
        const int k = t & 7, hh = (t >> 3) & 7;
        const float* vb = qkv + (size_t)(b * NN) * 192 + 128 + hh * 8 + k;
        float acc = 0.f;
#pragma unroll 4
        for (int i = 0; i < 128; ++i) {
            const int m = w * 128 + i;
            acc = fmaf(__expf(Es[m * 8 + hh] - SMAX), vb[(size_t)m * 192], acc);
        }
        red[t] = acc;
    }
    __syncthreads();
    if (t < 64) {
        const int hh = t >> 3;
        vfin[t] = (red[t] + red[64 + t] + red[128 + t] + red[192 + t]) * invden[hh] * centr[hh];
    }
    __syncthreads();
    // ---- n_out = vfin @ On ----
    {
        float acc = 0.f;
#pragma unroll
        for (int i = w * 16; i < w * 16 + 16; ++i)
            acc = fmaf(vfin[i], On[i * 64 + l], acc);
        red[t] = acc;
    }
    __syncthreads();
    if (t < 64) {
        n_out[(size_t)bn * 64 + t] = red[t] + red[64 + t] + red[128 + t] + red[192 + t];
    }
}

extern "C" void kernel_launch(void* const* d_in, const int* in_sizes, int n_in,
                              void* d_out, int out_size, void* d_ws, size_t ws_size,
                              hipStream_t stream) {
    const float* n_in_p = (const float*)d_in[0];
    const float* e_p    = (const float*)d_in[1];
    const float* Wqkv   = (const float*)d_in[2];
    const float* On     = (const float*)d_in[3];
    const float* Wg     = (const float*)d_in[4];
    const float* We     = (const float*)d_in[5];
    const float* Oe     = (const float*)d_in[6];
    float* out = (float*)d_out;
    float* n_out = out;                              // 4*512*64
    float* e_out = out + (size_t)4 * 512 * 64;       // 4*512*512*64
    float* qkv = (float*)d_ws;                       // 4*512*192 floats

    hipLaunchKernelGGL(qkv_proj, dim3(4 * NN), dim3(64), 0, stream, n_in_p, Wqkv, qkv);
    hipLaunchKernelGGL(edge_all, dim3(4 * NN), dim3(256), 0, stream,
                       e_p, qkv, We, Wg, Oe, On, n_out, e_out);
}

// Round 6
// 218.122 us; speedup vs baseline: 1.2488x; 1.1039x over previous
//
#include <hip/hip_runtime.h>

#define NN 512
#define SCALE 0.35355339059327373f  /* dk^-0.5, dk=8 */
#define SMAX 6.0f                   /* fixed softmax shift (exact ratios) */

// ---------------- K1: QKV projection ----------------
__global__ __launch_bounds__(64) void qkv_proj(const float* __restrict__ nin,
                                               const float* __restrict__ Wqkv,
                                               float* __restrict__ qkv) {
    const int r = blockIdx.x;
    const int j = threadIdx.x;
    const float* nr = nin + (size_t)r * 64;
    float a0 = 0.f, a1 = 0.f, a2 = 0.f;
#pragma unroll
    for (int d = 0; d < 64; ++d) {
        const float nv = nr[d];
        const float* wr = Wqkv + d * 192;
        a0 = fmaf(nv, wr[j], a0);
        a1 = fmaf(nv, wr[64 + j], a1);
        a2 = fmaf(nv, wr[128 + j], a2);
    }
    float* o = qkv + (size_t)r * 192;
    o[j] = a0; o[64 + j] = a1; o[128 + j] = a2;
}

__device__ __forceinline__ void gload16(const float* g, float* l) {
    __builtin_amdgcn_global_load_lds(
        (const __attribute__((address_space(1))) unsigned int*)(g),
        (__attribute__((address_space(3))) unsigned int*)(l), 16, 0, 0);
}

// ---------------- K2: fused edge kernel ----------------
// block=(b,n), 4 waves. Wave owns 128 m-rows (2 tiles x 64). Lane owns a row.
// e staged to per-wave LDS via global_load_lds (full-line requests), quarter-row
// (16-float) double-buffered segments, counted vmcnt. W/Q/Oe wave-uniform s_loads.
__global__ __launch_bounds__(256, 3) void edge_fused2(
    const float* __restrict__ e,
    const float* __restrict__ qkv,
    const float* __restrict__ We,   // (64,8)
    const float* __restrict__ Wg,   // (64,8)
    const float* __restrict__ Oe,   // (8,64)
    const float* __restrict__ On,   // (64,64)
    float* __restrict__ n_out,
    float* __restrict__ e_out)
{
    __shared__ float ebuf[4][2][64][16];  // per-wave dbuf quarter-row tiles (32 KB)
    __shared__ float Ps[NN * 8];          // P = exp(E-6), per row/head (16 KB)
    __shared__ float red[256];
    __shared__ float wdn[4][8], wgs[4][8];
    __shared__ float vfin[64];

    const int t = threadIdx.x, w = t >> 6, l = t & 63;
    const int bid = blockIdx.x;
    const int bn = (bid & 7) * 256 + (bid >> 3);   // XCD-chunked swizzle (2048%8==0)
    const int b = bn >> 9;
    const float* __restrict__ Q = qkv + (size_t)bn * 192;       // uniform -> s_load
    const float* __restrict__ ebase = e + (size_t)bn * 32768;
    float* __restrict__ eob = e_out + (size_t)bn * 32768;

    const int srow = l >> 2;                    // staging row-in-16-group
    const int sperm = (l & 3) ^ (srow & 3);     // XOR-swizzled source granule

    float dn[8], gs[8], ee[8], gg[8], ar[8];
#pragma unroll
    for (int j = 0; j < 8; ++j) { dn[j] = 0.f; gs[j] = 0.f; }

    // stage segment: 64 rows x 16 floats (d-quarter q) into buf (seg&1)
#define STAGE(seg) do {                                                          \
        const int rowb_ = w * 128 + (((seg) >> 2) << 6);                         \
        _Pragma("unroll")                                                        \
        for (int i_ = 0; i_ < 4; ++i_) {                                         \
            const int rloc_ = i_ * 16 + srow;                                    \
            gload16(ebase + (size_t)(rowb_ + rloc_) * 64 + ((seg) & 3) * 16 + sperm * 4, \
                    &ebuf[w][(seg) & 1][i_ * 16][0]);                            \
        } } while (0)

#define SEG(seg, tile, q, LAST) do {                                             \
        const int rowB = w * 128 + (tile) * 64 + l;                              \
        const float* kp = qkv + (size_t)(b * NN + rowB) * 192 + 64 + (q) * 16;   \
        float4 kk[4];                                                            \
        _Pragma("unroll")                                                        \
        for (int j_ = 0; j_ < 4; ++j_) kk[j_] = *(const float4*)(kp + j_ * 4);   \
        if (!(LAST)) STAGE((seg) + 1);                                           \
        asm volatile("s_waitcnt vmcnt(4)" ::: "memory");                         \
        if ((q) == 0) {                                                          \
            _Pragma("unroll")                                                    \
            for (int j_ = 0; j_ < 8; ++j_) { ee[j_] = 0.f; gg[j_] = 0.f; ar[j_] = 0.f; } \
        }                                                                        \
        _Pragma("unroll")                                                        \
        for (int j_ = 0; j_ < 4; ++j_) {                                         \
            const float4 ev = *(const float4*)&ebuf[w][(seg) & 1][l][((j_ ^ (l & 3)) << 2)]; \
            const float ec[4] = {ev.x, ev.y, ev.z, ev.w};                        \
            const float kc[4] = {kk[j_].x, kk[j_].y, kk[j_].z, kk[j_].w};        \
            _Pragma("unroll")                                                    \
            for (int cc = 0; cc < 4; ++cc) {                                     \
                const int d = (q) * 16 + j_ * 4 + cc;                            \
                const float4 wa = *(const float4*)(We + d * 8);                  \
                const float4 wb = *(const float4*)(We + d * 8 + 4);              \
                const float4 ga = *(const float4*)(Wg + d * 8);                  \
                const float4 gb = *(const float4*)(Wg + d * 8 + 4);              \
                const float evv = ec[cc];                                        \
                ee[0] = fmaf(evv, wa.x, ee[0]); ee[1] = fmaf(evv, wa.y, ee[1]);  \
                ee[2] = fmaf(evv, wa.z, ee[2]); ee[3] = fmaf(evv, wa.w, ee[3]);  \
                ee[4] = fmaf(evv, wb.x, ee[4]); ee[5] = fmaf(evv, wb.y, ee[5]);  \
                ee[6] = fmaf(evv, wb.z, ee[6]); ee[7] = fmaf(evv, wb.w, ee[7]);  \
                gg[0] = fmaf(evv, ga.x, gg[0]); gg[1] = fmaf(evv, ga.y, gg[1]);  \
                gg[2] = fmaf(evv, ga.z, gg[2]); gg[3] = fmaf(evv, ga.w, gg[3]);  \
                gg[4] = fmaf(evv, gb.x, gg[4]); gg[5] = fmaf(evv, gb.y, gg[5]);  \
                gg[6] = fmaf(evv, gb.z, gg[6]); gg[7] = fmaf(evv, gb.w, gg[7]);  \
                ar[d >> 3] = fmaf(kc[cc], Q[d], ar[d >> 3]);                     \
            }                                                                    \
        }                                                                        \
        if ((q) == 3) {                                                          \
            float E[8], P[8];                                                    \
            _Pragma("unroll")                                                    \
            for (int h_ = 0; h_ < 8; ++h_) {                                     \
                const float a_ = fminf(fmaxf(ar[h_] * SCALE, -5.f), 5.f);        \
                E[h_] = a_ + ee[h_];                                             \
                P[h_] = __expf(E[h_] - SMAX);                                    \
                dn[h_] += P[h_];                                                 \
                gs[h_] += 1.f / (1.f + __expf(-gg[h_]));                         \
            }                                                                    \
            *(float4*)&Ps[rowB * 8]     = make_float4(P[0], P[1], P[2], P[3]);   \
            *(float4*)&Ps[rowB * 8 + 4] = make_float4(P[4], P[5], P[6], P[7]);   \
            float* orow = eob + (size_t)rowB * 64;                               \
            _Pragma("unroll")                                                    \
            for (int j4 = 0; j4 < 16; ++j4) {                                    \
                const float4 o0 = *(const float4*)(Oe + 0 * 64 + j4 * 4);        \
                const float4 o1 = *(const float4*)(Oe + 1 * 64 + j4 * 4);        \
                const float4 o2 = *(const float4*)(Oe + 2 * 64 + j4 * 4);        \
                const float4 o3 = *(const float4*)(Oe + 3 * 64 + j4 * 4);        \
                const float4 o4 = *(const float4*)(Oe + 4 * 64 + j4 * 4);        \
                const float4 o5 = *(const float4*)(Oe + 5 * 64 + j4 * 4);        \
                const float4 o6 = *(const float4*)(Oe + 6 * 64 + j4 * 4);        \
                const float4 o7 = *(const float4*)(Oe + 7 * 64 + j4 * 4);        \
                float x0 = E[0] * o0.x, x1 = E[0] * o0.y, x2 = E[0] * o0.z, x3 = E[0] * o0.w; \
                x0 = fmaf(E[1], o1.x, x0); x1 = fmaf(E[1], o1.y, x1); x2 = fmaf(E[1], o1.z, x2); x3 = fmaf(E[1], o1.w, x3); \
                x0 = fmaf(E[2], o2.x, x0); x1 = fmaf(E[2], o2.y, x1); x2 = fmaf(E[2], o2.z, x2); x3 = fmaf(E[2], o2.w, x3); \
                x0 = fmaf(E[3], o3.x, x0); x1 = fmaf(E[3], o3.y, x1); x2 = fmaf(E[3], o3.z, x2); x3 = fmaf(E[3], o3.w, x3); \
                x0 = fmaf(E[4], o4.x, x0); x1 = fmaf(E[4], o4.y, x1); x2 = fmaf(E[4], o4.z, x2); x3 = fmaf(E[4], o4.w, x3); \
                x0 = fmaf(E[5], o5.x, x0); x1 = fmaf(E[5], o5.y, x1); x2 = fmaf(E[5], o5.z, x2); x3 = fmaf(E[5], o5.w, x3); \
                x0 = fmaf(E[6], o6.x, x0); x1 = fmaf(E[6], o6.y, x1); x2 = fmaf(E[6], o6.z, x2); x3 = fmaf(E[6], o6.w, x3); \
                x0 = fmaf(E[7], o7.x, x0); x1 = fmaf(E[7], o7.y, x1); x2 = fmaf(E[7], o7.z, x2); x3 = fmaf(E[7], o7.w, x3); \
                *(float4*)(orow + j4 * 4) = make_float4(x0, x1, x2, x3);         \
            }                                                                    \
        } } while (0)

    STAGE(0);
    SEG(0, 0, 0, 0); SEG(1, 0, 1, 0); SEG(2, 0, 2, 0); SEG(3, 0, 3, 0);
    SEG(4, 1, 0, 0); SEG(5, 1, 1, 0); SEG(6, 1, 2, 0); SEG(7, 1, 3, 1);

    // wave-reduce denominators & gate sums
#pragma unroll
    for (int off = 1; off < 64; off <<= 1) {
#pragma unroll
        for (int j = 0; j < 8; ++j) {
            dn[j] += __shfl_xor(dn[j], off, 64);
            gs[j] += __shfl_xor(gs[j], off, 64);
        }
    }
    if (l == 0) {
#pragma unroll
        for (int j = 0; j < 8; ++j) { wdn[w][j] = dn[j]; wgs[w][j] = gs[j]; }
    }
    __syncthreads();

    // ---- PV: thread=(k,h), wave scans its own 128 rows; V L2-hot ----
    {
        const int k = t & 7, hh = (t >> 3) & 7;
        const float* vb = qkv + (size_t)(b * NN) * 192 + 128 + hh * 8 + k;
        float acc = 0.f;
#pragma unroll 8
        for (int i = 0; i < 128; ++i) {
            const int m = w * 128 + i;
            acc = fmaf(Ps[m * 8 + hh], vb[(size_t)m * 192], acc);
        }
        red[t] = acc;
    }
    __syncthreads();
    if (t < 64) {
        const int hh = t >> 3;
        const float den = wdn[0][hh] + wdn[1][hh] + wdn[2][hh] + wdn[3][hh];
        const float gsum = wgs[0][hh] + wgs[1][hh] + wgs[2][hh] + wgs[3][hh];
        vfin[t] = (red[t] + red[64 + t] + red[128 + t] + red[192 + t]) * (1.f / den) * log1pf(gsum);
    }
    __syncthreads();
    // ---- n_out = vfin @ On ----
    {
        float acc = 0.f;
#pragma unroll
        for (int i = w * 16; i < w * 16 + 16; ++i)
            acc = fmaf(vfin[i], On[i * 64 + l], acc);
        red[t] = acc;
    }
    __syncthreads();
    if (t < 64)
        n_out[(size_t)bn * 64 + t] = red[t] + red[64 + t] + red[128 + t] + red[192 + t];
#undef STAGE
#undef SEG
}

extern "C" void kernel_launch(void* const* d_in, const int* in_sizes, int n_in,
                              void* d_out, int out_size, void* d_ws, size_t ws_size,
                              hipStream_t stream) {
    const float* n_in_p = (const float*)d_in[0];
    const float* e_p    = (const float*)d_in[1];
    const float* Wqkv   = (const float*)d_in[2];
    const float* On     = (const float*)d_in[3];
    const float* Wg     = (const float*)d_in[4];
    const float* We     = (const float*)d_in[5];
    const float* Oe     = (const float*)d_in[6];
    float* out = (float*)d_out;
    float* n_out = out;                              // 4*512*64
    float* e_out = out + (size_t)4 * 512 * 64;       // 4*512*512*64
    float* qkv = (float*)d_ws;                       // 4*512*192 floats

    hipLaunchKernelGGL(qkv_proj, dim3(4 * NN), dim3(64), 0, stream, n_in_p, Wqkv, qkv);
    hipLaunchKernelGGL(edge_fused2, dim3(4 * NN), dim3(256), 0, stream,
                       e_p, qkv, We, Wg, Oe, On, n_out, e_out);
}

// Round 7
// 217.860 us; speedup vs baseline: 1.2503x; 1.0012x over previous
//
#include <hip/hip_runtime.h>

#define NN 512
#define SCALE 0.35355339059327373f  /* dk^-0.5, dk=8 */
#define SMAX 6.0f                   /* fixed softmax shift (exact ratios) */

// ---------------- K1: QKV projection ----------------
__global__ __launch_bounds__(64) void qkv_proj(const float* __restrict__ nin,
                                               const float* __restrict__ Wqkv,
                                               float* __restrict__ qkv) {
    const int r = blockIdx.x;
    const int j = threadIdx.x;
    const float* nr = nin + (size_t)r * 64;
    float a0 = 0.f, a1 = 0.f, a2 = 0.f;
#pragma unroll
    for (int d = 0; d < 64; ++d) {
        const float nv = nr[d];
        const float* wr = Wqkv + d * 192;
        a0 = fmaf(nv, wr[j], a0);
        a1 = fmaf(nv, wr[64 + j], a1);
        a2 = fmaf(nv, wr[128 + j], a2);
    }
    float* o = qkv + (size_t)r * 192;
    o[j] = a0; o[64 + j] = a1; o[128 + j] = a2;
}

__device__ __forceinline__ void gload16(const float* g, float* l) {
    __builtin_amdgcn_global_load_lds(
        (const __attribute__((address_space(1))) unsigned int*)(g),
        (__attribute__((address_space(3))) unsigned int*)(l), 16, 0, 0);
}

#define WAITV(N) asm volatile("s_waitcnt vmcnt(" #N ")" ::: "memory")

// ---------------- K2: fused edge kernel, store-safe static schedule ----------
__global__ __launch_bounds__(256, 3) void edge_fused3(
    const float* __restrict__ e,
    const float* __restrict__ qkv,
    const float* __restrict__ We,   // (64,8)
    const float* __restrict__ Wg,   // (64,8)
    const float* __restrict__ Oe,   // (8,64)
    const float* __restrict__ On,   // (64,64)
    float* __restrict__ n_out,
    float* __restrict__ e_out)
{
    __shared__ float ebuf[4][2][64][16];  // per-wave dbuf tiles (32 KB)
    __shared__ float Ps[NN * 8];          // P = exp(E-6) (16 KB)
    __shared__ float red[256];
    __shared__ float wdn[4][8], wgs[4][8];
    __shared__ float vfin[64];

    const int t = threadIdx.x, w = t >> 6, l = t & 63;
    const int bid = blockIdx.x;
    const int bn = (bid & 7) * 256 + (bid >> 3);   // XCD-chunked swizzle
    const int b = bn >> 9;
    const float* __restrict__ Q = qkv + (size_t)bn * 192;     // uniform -> s_load
    const float* __restrict__ ebase = e + (size_t)bn * 32768;
    float* __restrict__ eob = e_out + (size_t)bn * 32768;

    const int srow = l >> 2;
    const int sperm = (l & 3) ^ ((srow >> 1) & 3);   // 8-way-conflict layout

    float dn[8], gs[8], ee[8], gg[8], ar[8];
#pragma unroll
    for (int j = 0; j < 8; ++j) { dn[j] = 0.f; gs[j] = 0.f; }

#define ISSUE_E(seg) do {                                                        \
        const int rowb_ = w * 128 + (((seg) >> 2) << 6);                         \
        _Pragma("unroll")                                                        \
        for (int i_ = 0; i_ < 4; ++i_) {                                         \
            gload16(ebase + (size_t)(rowb_ + i_ * 16 + srow) * 64 + ((seg) & 3) * 16 + sperm * 4, \
                    &ebuf[w][(seg) & 1][i_ * 16][0]);                            \
        } } while (0)

#define CSEG(seg, q) do {                                                        \
        if ((q) == 0) {                                                          \
            _Pragma("unroll")                                                    \
            for (int j_ = 0; j_ < 8; ++j_) { ee[j_] = 0.f; gg[j_] = 0.f; ar[j_] = 0.f; } \
        }                                                                        \
        _Pragma("unroll")                                                        \
        for (int j_ = 0; j_ < 4; ++j_) {                                         \
            const float4 ev = *(const float4*)&ebuf[w][(seg) & 1][l][((j_ ^ ((l >> 1) & 3)) << 2)]; \
            const float4 kv = kk[(q) * 4 + j_];                                  \
            const float ec[4] = {ev.x, ev.y, ev.z, ev.w};                        \
            const float kc[4] = {kv.x, kv.y, kv.z, kv.w};                        \
            _Pragma("unroll")                                                    \
            for (int cc = 0; cc < 4; ++cc) {                                     \
                const int d = (q) * 16 + j_ * 4 + cc;                            \
                const float4 wa = *(const float4*)(We + d * 8);                  \
                const float4 wb = *(const float4*)(We + d * 8 + 4);              \
                const float4 ga = *(const float4*)(Wg + d * 8);                  \
                const float4 gb = *(const float4*)(Wg + d * 8 + 4);              \
                const float evv = ec[cc];                                        \
                ee[0] = fmaf(evv, wa.x, ee[0]); ee[1] = fmaf(evv, wa.y, ee[1]);  \
                ee[2] = fmaf(evv, wa.z, ee[2]); ee[3] = fmaf(evv, wa.w, ee[3]);  \
                ee[4] = fmaf(evv, wb.x, ee[4]); ee[5] = fmaf(evv, wb.y, ee[5]);  \
                ee[6] = fmaf(evv, wb.z, ee[6]); ee[7] = fmaf(evv, wb.w, ee[7]);  \
                gg[0] = fmaf(evv, ga.x, gg[0]); gg[1] = fmaf(evv, ga.y, gg[1]);  \
                gg[2] = fmaf(evv, ga.z, gg[2]); gg[3] = fmaf(evv, ga.w, gg[3]);  \
                gg[4] = fmaf(evv, gb.x, gg[4]); gg[5] = fmaf(evv, gb.y, gg[5]);  \
                gg[6] = fmaf(evv, gb.z, gg[6]); gg[7] = fmaf(evv, gb.w, gg[7]);  \
                ar[d >> 3] = fmaf(kc[cc], Q[d], ar[d >> 3]);                     \
            }                                                                    \
        } } while (0)

#define FIN(tile, Ename, Pname) do {                                             \
        _Pragma("unroll")                                                        \
        for (int h_ = 0; h_ < 8; ++h_) {                                         \
            const float a_ = fminf(fmaxf(ar[h_] * SCALE, -5.f), 5.f);            \
            Ename[h_] = a_ + ee[h_];                                             \
            Pname[h_] = __expf(Ename[h_] - SMAX);                                \
            dn[h_] += Pname[h_];                                                 \
            gs[h_] += 1.f / (1.f + __expf(-gg[h_]));                             \
        }                                                                        \
        const int rowB_ = w * 128 + (tile) * 64 + l;                             \
        *(float4*)&Ps[rowB_ * 8]     = make_float4(Pname[0], Pname[1], Pname[2], Pname[3]); \
        *(float4*)&Ps[rowB_ * 8 + 4] = make_float4(Pname[4], Pname[5], Pname[6], Pname[7]); \
    } while (0)

#define EOUT(tile, Ename) do {                                                   \
        float* orow = eob + (size_t)(w * 128 + (tile) * 64 + l) * 64;            \
        _Pragma("unroll")                                                        \
        for (int j4 = 0; j4 < 16; ++j4) {                                        \
            const float4 o0 = *(const float4*)(Oe + 0 * 64 + j4 * 4);            \
            const float4 o1 = *(const float4*)(Oe + 1 * 64 + j4 * 4);            \
            const float4 o2 = *(const float4*)(Oe + 2 * 64 + j4 * 4);            \
            const float4 o3 = *(const float4*)(Oe + 3 * 64 + j4 * 4);            \
            const float4 o4 = *(const float4*)(Oe + 4 * 64 + j4 * 4);            \
            const float4 o5 = *(const float4*)(Oe + 5 * 64 + j4 * 4);            \
            const float4 o6 = *(const float4*)(Oe + 6 * 64 + j4 * 4);            \
            const float4 o7 = *(const float4*)(Oe + 7 * 64 + j4 * 4);            \
            float x0 = Ename[0] * o0.x, x1 = Ename[0] * o0.y, x2 = Ename[0] * o0.z, x3 = Ename[0] * o0.w; \
            x0 = fmaf(Ename[1], o1.x, x0); x1 = fmaf(Ename[1], o1.y, x1); x2 = fmaf(Ename[1], o1.z, x2); x3 = fmaf(Ename[1], o1.w, x3); \
            x0 = fmaf(Ename[2], o2.x, x0); x1 = fmaf(Ename[2], o2.y, x1); x2 = fmaf(Ename[2], o2.z, x2); x3 = fmaf(Ename[2], o2.w, x3); \
            x0 = fmaf(Ename[3], o3.x, x0); x1 = fmaf(Ename[3], o3.y, x1); x2 = fmaf(Ename[3], o3.z, x2); x3 = fmaf(Ename[3], o3.w, x3); \
            x0 = fmaf(Ename[4], o4.x, x0); x1 = fmaf(Ename[4], o4.y, x1); x2 = fmaf(Ename[4], o4.z, x2); x3 = fmaf(Ename[4], o4.w, x3); \
            x0 = fmaf(Ename[5], o5.x, x0); x1 = fmaf(Ename[5], o5.y, x1); x2 = fmaf(Ename[5], o5.z, x2); x3 = fmaf(Ename[5], o5.w, x3); \
            x0 = fmaf(Ename[6], o6.x, x0); x1 = fmaf(Ename[6], o6.y, x1); x2 = fmaf(Ename[6], o6.z, x2); x3 = fmaf(Ename[6], o6.w, x3); \
            x0 = fmaf(Ename[7], o7.x, x0); x1 = fmaf(Ename[7], o7.y, x1); x2 = fmaf(Ename[7], o7.z, x2); x3 = fmaf(Ename[7], o7.w, x3); \
            *(float4*)(orow + j4 * 4) = make_float4(x0, x1, x2, x3);             \
        } } while (0)

    // ---- prologue: K tile0 (16 float4, before any store exists) + first stage
    float4 kk[16];
    {
        const float* kb = qkv + (size_t)(b * NN + w * 128 + l) * 192 + 64;
#pragma unroll
        for (int j = 0; j < 16; ++j) kk[j] = *(const float4*)(kb + j * 4);
    }
    ISSUE_E(0);

    float E0r[8], P0r[8], E1r[8], P1r[8];

    ISSUE_E(1); WAITV(4);  CSEG(0, 0);                 // [E1]
    ISSUE_E(2); WAITV(4);  CSEG(1, 1);                 // [E2]
    ISSUE_E(3); WAITV(4);  CSEG(2, 2);                 // [E3]
    ISSUE_E(4); WAITV(4);  CSEG(3, 3);                 // [E4]
    FIN(0, E0r, P0r);
    {   // K tile1 reload (kk dead) — still no stores in flight
        const float* kb = qkv + (size_t)(b * NN + w * 128 + 64 + l) * 192 + 64;
#pragma unroll
        for (int j = 0; j < 16; ++j) kk[j] = *(const float4*)(kb + j * 4);
    }
    ISSUE_E(5); WAITV(4);                              // retires E4+K1 -> [E5]
    EOUT(0, E0r);                                      // S0 issued here -> [E5,S0]
    CSEG(4, 0);
    ISSUE_E(6); WAITV(20); CSEG(5, 1);                 // retire E5 -> [S0,E6]
    ISSUE_E(7); WAITV(4);  CSEG(6, 2);                 // drains stale S0 -> [E7]
    WAITV(0);              CSEG(7, 3);
    FIN(1, E1r, P1r);
    EOUT(1, E1r);                                      // S1 issued, drains later

    // ---- gate/denominator wave reductions (DS ops cover S1 head start) ----
#pragma unroll
    for (int off = 1; off < 64; off <<= 1) {
#pragma unroll
        for (int j = 0; j < 8; ++j) {
            dn[j] += __shfl_xor(dn[j], off, 64);
            gs[j] += __shfl_xor(gs[j], off, 64);
        }
    }
    if (l == 0) {
#pragma unroll
        for (int j = 0; j < 8; ++j) { wdn[w][j] = dn[j]; wgs[w][j] = gs[j]; }
    }

    // ---- PV: own-wave rows only (no barrier needed before this) ----
    {
        const int k = t & 7, hh = (t >> 3) & 7;
        const float* vb = qkv + (size_t)(b * NN) * 192 + 128 + hh * 8 + k;
        float acc = 0.f;
#pragma unroll 8
        for (int i = 0; i < 128; ++i) {
            const int m = w * 128 + i;
            acc = fmaf(Ps[m * 8 + hh], vb[(size_t)m * 192], acc);
        }
        red[t] = acc;
    }
    __syncthreads();
    if (t < 64) {
        const int hh = t >> 3;
        const float den = wdn[0][hh] + wdn[1][hh] + wdn[2][hh] + wdn[3][hh];
        const float gsum = wgs[0][hh] + wgs[1][hh] + wgs[2][hh] + wgs[3][hh];
        vfin[t] = (red[t] + red[64 + t] + red[128 + t] + red[192 + t]) * (1.f / den) * log1pf(gsum);
    }
    __syncthreads();
    {
        float acc = 0.f;
#pragma unroll
        for (int i = w * 16; i < w * 16 + 16; ++i)
            acc = fmaf(vfin[i], On[i * 64 + l], acc);
        red[t] = acc;
    }
    __syncthreads();
    if (t < 64)
        n_out[(size_t)bn * 64 + t] = red[t] + red[64 + t] + red[128 + t] + red[192 + t];

#undef ISSUE_E
#undef CSEG
#undef FIN
#undef EOUT
}

extern "C" void kernel_launch(void* const* d_in, const int* in_sizes, int n_in,
                              void* d_out, int out_size, void* d_ws, size_t ws_size,
                              hipStream_t stream) {
    const float* n_in_p = (const float*)d_in[0];
    const float* e_p    = (const float*)d_in[1];
    const float* Wqkv   = (const float*)d_in[2];
    const float* On     = (const float*)d_in[3];
    const float* Wg     = (const float*)d_in[4];
    const float* We     = (const float*)d_in[5];
    const float* Oe     = (const float*)d_in[6];
    float* out = (float*)d_out;
    float* n_out = out;                              // 4*512*64
    float* e_out = out + (size_t)4 * 512 * 64;       // 4*512*512*64
    float* qkv = (float*)d_ws;                       // 4*512*192 floats

    hipLaunchKernelGGL(qkv_proj, dim3(4 * NN), dim3(64), 0, stream, n_in_p, Wqkv, qkv);
    hipLaunchKernelGGL(edge_fused3, dim3(4 * NN), dim3(256), 0, stream,
                       e_p, qkv, We, Wg, Oe, On, n_out, e_out);
}

// Round 9
// 215.502 us; speedup vs baseline: 1.2640x; 1.0109x over previous
//
#include <hip/hip_runtime.h>

#define NN 512
#define SCALE 0.35355339059327373f  /* dk^-0.5, dk=8 */
#define SMAX 6.0f                   /* fixed softmax shift (exact ratios) */

// ---------------- K1: QKV projection ----------------
__global__ __launch_bounds__(64) void qkv_proj(const float* __restrict__ nin,
                                               const float* __restrict__ Wqkv,
                                               float* __restrict__ qkv) {
    const int r = blockIdx.x;
    const int j = threadIdx.x;
    const float* nr = nin + (size_t)r * 64;
    float a0 = 0.f, a1 = 0.f, a2 = 0.f;
#pragma unroll
    for (int d = 0; d < 64; ++d) {
        const float nv = nr[d];
        const float* wr = Wqkv + d * 192;
        a0 = fmaf(nv, wr[j], a0);
        a1 = fmaf(nv, wr[64 + j], a1);
        a2 = fmaf(nv, wr[128 + j], a2);
    }
    float* o = qkv + (size_t)r * 192;
    o[j] = a0; o[64 + j] = a1; o[128 + j] = a2;
}

__device__ __forceinline__ void gload16(const float* g, float* l) {
    __builtin_amdgcn_global_load_lds(
        (const __attribute__((address_space(1))) unsigned int*)(g),
        (__attribute__((address_space(3))) unsigned int*)(l), 16, 0, 0);
}
#define WAITV(N) asm volatile("s_waitcnt vmcnt(" #N ")" ::: "memory")
#define BARRIER() __builtin_amdgcn_s_barrier()

// ---------------- K2: scores + stash + PV + n_out ----------------
// r7 structure + raw-s_barrier phase anchors (m201 pattern) so the memory
// legalizer stops injecting vmcnt(0) before ebuf ds_reads. e_out moved to K3.
__global__ __launch_bounds__(256, 3) void edge_score3(
    const float* __restrict__ e,
    const float* __restrict__ qkv,
    const float* __restrict__ We,   // (64,8)
    const float* __restrict__ Wg,   // (64,8)
    const float* __restrict__ On,   // (64,64)
    float* __restrict__ n_out,
    float* __restrict__ e_out)      // row head gets the _E stash
{
    __shared__ float ebuf[4][2][64][16];  // per-wave dbuf tiles (32 KB)
    __shared__ float Ps[NN * 8];          // P = exp(E-6) (16 KB)
    __shared__ float red[256];
    __shared__ float wdn[4][8], wgs[4][8];
    __shared__ float vfin[64];

    const int t = threadIdx.x, w = t >> 6, l = t & 63;
    const int bid = blockIdx.x;
    const int bn = (bid & 7) * 256 + (bid >> 3);   // XCD-chunked swizzle
    const int b = bn >> 9;
    const float* __restrict__ Q = qkv + (size_t)bn * 192;     // uniform -> s_load
    const float* __restrict__ ebase = e + (size_t)bn * 32768;
    float* __restrict__ eob = e_out + (size_t)bn * 32768;

    const int srow = l >> 2;
    const int sperm = (l & 3) ^ ((srow >> 1) & 3);   // 8-way-conflict layout

    float dn[8], gs[8], ee[8], gg[8], ar[8];
#pragma unroll
    for (int j = 0; j < 8; ++j) { dn[j] = 0.f; gs[j] = 0.f; }

#define ISSUE_E(seg) do {                                                        \
        const int rowb_ = w * 128 + (((seg) >> 2) << 6);                         \
        _Pragma("unroll")                                                        \
        for (int i_ = 0; i_ < 4; ++i_) {                                         \
            gload16(ebase + (size_t)(rowb_ + i_ * 16 + srow) * 64 + ((seg) & 3) * 16 + sperm * 4, \
                    &ebuf[w][(seg) & 1][i_ * 16][0]);                            \
        } } while (0)

#define CSEG(seg, q) do {                                                        \
        if ((q) == 0) {                                                          \
            _Pragma("unroll")                                                    \
            for (int j_ = 0; j_ < 8; ++j_) { ee[j_] = 0.f; gg[j_] = 0.f; ar[j_] = 0.f; } \
        }                                                                        \
        _Pragma("unroll")                                                        \
        for (int j_ = 0; j_ < 4; ++j_) {                                         \
            const float4 ev = *(const float4*)&ebuf[w][(seg) & 1][l][((j_ ^ ((l >> 1) & 3)) << 2)]; \
            const float4 kv = kk[(q) * 4 + j_];                                  \
            const float ec[4] = {ev.x, ev.y, ev.z, ev.w};                        \
            const float kc[4] = {kv.x, kv.y, kv.z, kv.w};                        \
            _Pragma("unroll")                                                    \
            for (int cc = 0; cc < 4; ++cc) {                                     \
                const int d = (q) * 16 + j_ * 4 + cc;                            \
                const float4 wa = *(const float4*)(We + d * 8);                  \
                const float4 wb = *(const float4*)(We + d * 8 + 4);              \
                const float4 ga = *(const float4*)(Wg + d * 8);                  \
                const float4 gb = *(const float4*)(Wg + d * 8 + 4);              \
                const float evv = ec[cc];                                        \
                ee[0] = fmaf(evv, wa.x, ee[0]); ee[1] = fmaf(evv, wa.y, ee[1]);  \
                ee[2] = fmaf(evv, wa.z, ee[2]); ee[3] = fmaf(evv, wa.w, ee[3]);  \
                ee[4] = fmaf(evv, wb.x, ee[4]); ee[5] = fmaf(evv, wb.y, ee[5]);  \
                ee[6] = fmaf(evv, wb.z, ee[6]); ee[7] = fmaf(evv, wb.w, ee[7]);  \
                gg[0] = fmaf(evv, ga.x, gg[0]); gg[1] = fmaf(evv, ga.y, gg[1]);  \
                gg[2] = fmaf(evv, ga.z, gg[2]); gg[3] = fmaf(evv, ga.w, gg[3]);  \
                gg[4] = fmaf(evv, gb.x, gg[4]); gg[5] = fmaf(evv, gb.y, gg[5]);  \
                gg[6] = fmaf(evv, gb.z, gg[6]); gg[7] = fmaf(evv, gb.w, gg[7]);  \
                ar[d >> 3] = fmaf(kc[cc], Q[d], ar[d >> 3]);                     \
            }                                                                    \
        } } while (0)

#define FIN(tile, Ename, Pname) do {                                             \
        _Pragma("unroll")                                                        \
        for (int h_ = 0; h_ < 8; ++h_) {                                         \
            const float a_ = fminf(fmaxf(ar[h_] * SCALE, -5.f), 5.f);            \
            Ename[h_] = a_ + ee[h_];                                             \
            Pname[h_] = __expf(Ename[h_] - SMAX);                                \
            dn[h_] += Pname[h_];                                                 \
            gs[h_] += 1.f / (1.f + __expf(-gg[h_]));                             \
        }                                                                        \
        const int rowB_ = w * 128 + (tile) * 64 + l;                             \
        *(float4*)&Ps[rowB_ * 8]     = make_float4(Pname[0], Pname[1], Pname[2], Pname[3]); \
        *(float4*)&Ps[rowB_ * 8 + 4] = make_float4(Pname[4], Pname[5], Pname[6], Pname[7]); \
        float* so_ = eob + (size_t)rowB_ * 8;   /* _E stash, [m][h] row-major */ \
        *(float4*)(so_)     = make_float4(Ename[0], Ename[1], Ename[2], Ename[3]); \
        *(float4*)(so_ + 4) = make_float4(Ename[4], Ename[5], Ename[6], Ename[7]); \
    } while (0)

    // ---- prologue: K tile0 (16 float4, before any store exists) + first stage
    float4 kk[16];
    {
        const float* kb = qkv + (size_t)(b * NN + w * 128 + l) * 192 + 64;
#pragma unroll
        for (int j = 0; j < 16; ++j) kk[j] = *(const float4*)(kb + j * 4);
    }
    ISSUE_E(0);

    float E0r[8], P0r[8], E1r[8], P1r[8];

    ISSUE_E(1); BARRIER(); WAITV(4); CSEG(0, 0);
    ISSUE_E(2); BARRIER(); WAITV(4); CSEG(1, 1);
    ISSUE_E(3); BARRIER(); WAITV(4); CSEG(2, 2);
    ISSUE_E(4); BARRIER(); WAITV(4); CSEG(3, 3);
    FIN(0, E0r, P0r);                               // Ps + 2 stash stores
    {   // K tile1 reload (kk dead)
        const float* kb = qkv + (size_t)(b * NN + w * 128 + 64 + l) * 192 + 64;
#pragma unroll
        for (int j = 0; j < 16; ++j) kk[j] = *(const float4*)(kb + j * 4);
    }
    ISSUE_E(5); BARRIER(); WAITV(4); CSEG(4, 0);    // drains E4+stash+K1
    ISSUE_E(6); BARRIER(); WAITV(4); CSEG(5, 1);
    ISSUE_E(7); BARRIER(); WAITV(4); CSEG(6, 2);
    BARRIER();  WAITV(0);            CSEG(7, 3);
    FIN(1, E1r, P1r);                               // stash drains under PV

    // ---- gate/denominator wave reductions ----
#pragma unroll
    for (int off = 1; off < 64; off <<= 1) {
#pragma unroll
        for (int j = 0; j < 8; ++j) {
            dn[j] += __shfl_xor(dn[j], off, 64);
            gs[j] += __shfl_xor(gs[j], off, 64);
        }
    }
    if (l == 0) {
#pragma unroll
        for (int j = 0; j < 8; ++j) { wdn[w][j] = dn[j]; wgs[w][j] = gs[j]; }
    }

    // ---- PV: own-wave rows only ----
    {
        const int k = t & 7, hh = (t >> 3) & 7;
        const float* vb = qkv + (size_t)(b * NN) * 192 + 128 + hh * 8 + k;
        float acc = 0.f;
#pragma unroll 8
        for (int i = 0; i < 128; ++i) {
            const int m = w * 128 + i;
            acc = fmaf(Ps[m * 8 + hh], vb[(size_t)m * 192], acc);
        }
        red[t] = acc;
    }
    __syncthreads();
    if (t < 64) {
        const int hh = t >> 3;
        const float den = wdn[0][hh] + wdn[1][hh] + wdn[2][hh] + wdn[3][hh];
        const float gsum = wgs[0][hh] + wgs[1][hh] + wgs[2][hh] + wgs[3][hh];
        vfin[t] = (red[t] + red[64 + t] + red[128 + t] + red[192 + t]) * (1.f / den) * log1pf(gsum);
    }
    __syncthreads();
    {
        float acc = 0.f;
#pragma unroll
        for (int i = w * 16; i < w * 16 + 16; ++i)
            acc = fmaf(vfin[i], On[i * 64 + l], acc);
        red[t] = acc;
    }
    __syncthreads();
    if (t < 64)
        n_out[(size_t)bn * 64 + t] = red[t] + red[64 + t] + red[128 + t] + red[192 + t];

#undef ISSUE_E
#undef CSEG
#undef FIN
}

// ---------------- K3: e_out = _E @ Oe (pure streaming, r3-proven) ----------
__global__ __launch_bounds__(256) void edge_out_stream(
    const float* __restrict__ Oe,   // (8,64)
    float* __restrict__ e_out)      // (B,N,N,64); row head holds the _E stash
{
    __shared__ float Es[NN * 8];    // 16 KB
    const int t = threadIdx.x;
    const int w = t >> 6;
    const int l = t & 63;
    const int bn = blockIdx.x;
    float* erow = e_out + (size_t)bn * 32768;

    {   // stash -> LDS (coalesced)
        const float4* src = reinterpret_cast<const float4*>(erow);
        float4* dst = reinterpret_cast<float4*>(Es);
#pragma unroll
        for (int i = 0; i < 4; ++i) dst[t + 256 * i] = src[t + 256 * i];
    }
    __syncthreads();

    const int j4 = l & 15, mr = l >> 4;
    float oc[8][4];
#pragma unroll
    for (int h = 0; h < 8; ++h) {
        const float4 v = reinterpret_cast<const float4*>(Oe + h * 64 + j4 * 4)[0];
        oc[h][0] = v.x; oc[h][1] = v.y; oc[h][2] = v.z; oc[h][3] = v.w;
    }
#pragma unroll 4
    for (int p = 0; p < 32; ++p) {
        const int m = w * 128 + p * 4 + mr;
        const float* er = Es + m * 8;
        const float4 ra = reinterpret_cast<const float4*>(er)[0];
        const float4 rb = reinterpret_cast<const float4*>(er)[1];
        float o0 = ra.x * oc[0][0], o1 = ra.x * oc[0][1], o2 = ra.x * oc[0][2], o3 = ra.x * oc[0][3];
        o0 = fmaf(ra.y, oc[1][0], o0); o1 = fmaf(ra.y, oc[1][1], o1); o2 = fmaf(ra.y, oc[1][2], o2); o3 = fmaf(ra.y, oc[1][3], o3);
        o0 = fmaf(ra.z, oc[2][0], o0); o1 = fmaf(ra.z, oc[2][1], o1); o2 = fmaf(ra.z, oc[2][2], o2); o3 = fmaf(ra.z, oc[2][3], o3);
        o0 = fmaf(ra.w, oc[3][0], o0); o1 = fmaf(ra.w, oc[3][1], o1); o2 = fmaf(ra.w, oc[3][2], o2); o3 = fmaf(ra.w, oc[3][3], o3);
        o0 = fmaf(rb.x, oc[4][0], o0); o1 = fmaf(rb.x, oc[4][1], o1); o2 = fmaf(rb.x, oc[4][2], o2); o3 = fmaf(rb.x, oc[4][3], o3);
        o0 = fmaf(rb.y, oc[5][0], o0); o1 = fmaf(rb.y, oc[5][1], o1); o2 = fmaf(rb.y, oc[5][2], o2); o3 = fmaf(rb.y, oc[5][3], o3);
        o0 = fmaf(rb.z, oc[6][0], o0); o1 = fmaf(rb.z, oc[6][1], o1); o2 = fmaf(rb.z, oc[6][2], o2); o3 = fmaf(rb.z, oc[6][3], o3);
        o0 = fmaf(rb.w, oc[7][0], o0); o1 = fmaf(rb.w, oc[7][1], o1); o2 = fmaf(rb.w, oc[7][2], o2); o3 = fmaf(rb.w, oc[7][3], o3);
        reinterpret_cast<float4*>(erow + (size_t)m * 64 + j4 * 4)[0] = make_float4(o0, o1, o2, o3);
    }
}

extern "C" void kernel_launch(void* const* d_in, const int* in_sizes, int n_in,
                              void* d_out, int out_size, void* d_ws, size_t ws_size,
                              hipStream_t stream) {
    const float* n_in_p = (const float*)d_in[0];
    const float* e_p    = (const float*)d_in[1];
    const float* Wqkv   = (const float*)d_in[2];
    const float* On     = (const float*)d_in[3];
    const float* Wg     = (const float*)d_in[4];
    const float* We     = (const float*)d_in[5];
    const float* Oe     = (const float*)d_in[6];
    float* out = (float*)d_out;
    float* n_out = out;                              // 4*512*64
    float* e_out = out + (size_t)4 * 512 * 64;       // 4*512*512*64
    float* qkv = (float*)d_ws;                       // 4*512*192 floats

    hipLaunchKernelGGL(qkv_proj, dim3(4 * NN), dim3(64), 0, stream, n_in_p, Wqkv, qkv);
    hipLaunchKernelGGL(edge_score3, dim3(4 * NN), dim3(256), 0, stream,
                       e_p, qkv, We, Wg, On, n_out, e_out);
    hipLaunchKernelGGL(edge_out_stream, dim3(4 * NN), dim3(256), 0, stream,
                       Oe, e_out);
}

// Round 10
// 209.315 us; speedup vs baseline: 1.3013x; 1.0296x over previous
//
#include <hip/hip_runtime.h>

#define NN 512
#define SCALE 0.35355339059327373f  /* dk^-0.5, dk=8 */
#define SMAX 6.0f                   /* fixed softmax shift (exact ratios) */

typedef short bf16x8 __attribute__((ext_vector_type(8)));
typedef float f32x4 __attribute__((ext_vector_type(4)));

__device__ __forceinline__ unsigned short bhi16(float x) {
    return (unsigned short)(__float_as_uint(x) >> 16);
}
__device__ __forceinline__ float btrunc(float x) {
    return __uint_as_float(__float_as_uint(x) & 0xFFFF0000u);
}
__device__ __forceinline__ unsigned short blo16(float x) {
    return (unsigned short)(__float_as_uint(x - btrunc(x)) >> 16);
}

// ---------------- K1: QKV projection ----------------
__global__ __launch_bounds__(64) void qkv_proj(const float* __restrict__ nin,
                                               const float* __restrict__ Wqkv,
                                               float* __restrict__ qkv) {
    const int r = blockIdx.x;
    const int j = threadIdx.x;
    const float* nr = nin + (size_t)r * 64;
    float a0 = 0.f, a1 = 0.f, a2 = 0.f;
#pragma unroll
    for (int d = 0; d < 64; ++d) {
        const float nv = nr[d];
        const float* wr = Wqkv + d * 192;
        a0 = fmaf(nv, wr[j], a0);
        a1 = fmaf(nv, wr[64 + j], a1);
        a2 = fmaf(nv, wr[128 + j], a2);
    }
    float* o = qkv + (size_t)r * 192;
    o[j] = a0; o[64 + j] = a1; o[128 + j] = a2;
}

__device__ __forceinline__ void gload16(const float* g, float* l) {
    __builtin_amdgcn_global_load_lds(
        (const __attribute__((address_space(1))) unsigned int*)(g),
        (__attribute__((address_space(3))) unsigned int*)(l), 16, 0, 0);
}
#define WAITV(N) asm volatile("s_waitcnt vmcnt(" #N ")" ::: "memory")
#define BARRIER() __builtin_amdgcn_s_barrier()
#define SBAR() __builtin_amdgcn_sched_barrier(0)

// ---------------- K2: split-bf16 MFMA scores + PV + n_out ----------------
// block=(b,n), 4 waves; wave owns 128 rows = 8 slabs of 16.
// Per slab: e staged via global_load_lds (full-line, 4-bit XOR granule swizzle);
// [ee|gg] = e @ [We|Wg] via 6 MFMAs (split-bf16: (e_hi+e_lo)W_hi + e_hi W_lo);
// QK via 2 MFMAs with block-diagonal Q_hi operand. Weights live in 10 bf16x8
// B-fragments (40 VGPRs) -- no per-segment scalar-load flood.
__global__ __launch_bounds__(256, 3) void edge_mfma2(
    const float* __restrict__ e,
    const float* __restrict__ qkv,
    const float* __restrict__ We,   // (64,8)
    const float* __restrict__ Wg,   // (64,8)
    const float* __restrict__ On,   // (64,64)
    float* __restrict__ n_out,
    float* __restrict__ e_out)      // row head gets the _E stash
{
    __shared__ float ebuf[4][2][16][64];  // per-wave slab dbuf (32 KB)
    __shared__ float E_lds[4][128][8];    // per-wave E scores (16 KB)
    __shared__ float red[256];
    __shared__ float wdn[4][8], wgs[4][8];
    __shared__ float vfin[64];

    const int t = threadIdx.x, w = t >> 6, l = t & 63;
    const int a2 = l >> 4;      // k-block / D row-group
    const int m16 = l & 15;     // A-row / B-col / D-col
    const int bid = blockIdx.x;
    const int bn = (bid & 7) * 256 + (bid >> 3);   // XCD-chunked swizzle
    const int b = bn >> 9;
    const int rowbase = w * 128;
    const float* __restrict__ Q = qkv + (size_t)bn * 192;
    const float* __restrict__ ebase = e + (size_t)bn * 32768;
    float* __restrict__ eob = e_out + (size_t)bn * 32768;

    // ---- prologue: persistent B-fragments ----
    bf16x8 WfB[4], WcB[2], QdB[2];
#pragma unroll
    for (int blk = 0; blk < 4; ++blk) {
#pragma unroll
        for (int jj = 0; jj < 4; ++jj) {
            const int d = blk * 16 + a2 * 4 + jj;
            const float wv = (m16 < 8) ? We[d * 8 + m16] : Wg[d * 8 + m16 - 8];
            const short h = (short)bhi16(wv);
            WfB[blk][2 * jj] = h;          // A pairs (e_hi, e_lo) x same W_hi
            WfB[blk][2 * jj + 1] = h;
        }
    }
#pragma unroll
    for (int c = 0; c < 2; ++c) {
        const int head = c * 4 + a2;       // = d>>3 for this lane's k-slots
#pragma unroll
        for (int j = 0; j < 8; ++j) {
            const int d = c * 32 + a2 * 8 + j;
            const float wv = (m16 < 8) ? We[d * 8 + m16] : Wg[d * 8 + m16 - 8];
            WcB[c][j] = (short)blo16(wv);
            QdB[c][j] = (m16 == head) ? (short)bhi16(Q[d]) : (short)0;
        }
    }
    float dn = 0.f, gs = 0.f;
    SBAR();

#define STAGE(s) do {                                                            \
        _Pragma("unroll")                                                        \
        for (int i_ = 0; i_ < 4; ++i_) {                                         \
            const int lrow_ = i_ * 4 + (l >> 4);                                 \
            gload16(ebase + (size_t)(rowbase + (s) * 16 + lrow_) * 64            \
                        + (((l & 15) ^ lrow_) * 4),                              \
                    &ebuf[w][(s) & 1][i_ * 4][0]);                               \
        } } while (0)

#define SLAB(s, WN) do {                                                         \
        float4 kq0, kq1, kq2, kq3;                                               \
        { const float* kp_ = qkv + (size_t)(b * NN + rowbase + (s) * 16 + m16) * 192 \
                             + 64 + a2 * 8;                                      \
          kq0 = *(const float4*)(kp_);      kq1 = *(const float4*)(kp_ + 4);     \
          kq2 = *(const float4*)(kp_ + 32); kq3 = *(const float4*)(kp_ + 36); }  \
        SBAR();                                                                  \
        if ((s) < 7) STAGE((s) + 1);                                             \
        SBAR(); BARRIER(); WAITV(WN); SBAR();                                    \
        f32x4 c1 = {0.f, 0.f, 0.f, 0.f}, c2 = {0.f, 0.f, 0.f, 0.f};             \
        _Pragma("unroll")                                                        \
        for (int blk = 0; blk < 4; ++blk) {                                      \
            const float4 ev = *(const float4*)&ebuf[w][(s) & 1][m16]             \
                                  [(((blk * 4 + a2) ^ m16) * 4)];                \
            bf16x8 af;                                                           \
            af[0] = (short)bhi16(ev.x); af[1] = (short)blo16(ev.x);              \
            af[2] = (short)bhi16(ev.y); af[3] = (short)blo16(ev.y);              \
            af[4] = (short)bhi16(ev.z); af[5] = (short)blo16(ev.z);              \
            af[6] = (short)bhi16(ev.w); af[7] = (short)blo16(ev.w);              \
            c1 = __builtin_amdgcn_mfma_f32_16x16x32_bf16(af, WfB[blk], c1, 0, 0, 0); \
        }                                                                        \
        _Pragma("unroll")                                                        \
        for (int c = 0; c < 2; ++c) {                                            \
            const int g0 = c * 8 + a2 * 2;                                       \
            const float4 e0 = *(const float4*)&ebuf[w][(s) & 1][m16][((g0 ^ m16) * 4)]; \
            const float4 e1 = *(const float4*)&ebuf[w][(s) & 1][m16][(((g0 + 1) ^ m16) * 4)]; \
            bf16x8 ac;                                                           \
            ac[0] = (short)bhi16(e0.x); ac[1] = (short)bhi16(e0.y);              \
            ac[2] = (short)bhi16(e0.z); ac[3] = (short)bhi16(e0.w);              \
            ac[4] = (short)bhi16(e1.x); ac[5] = (short)bhi16(e1.y);              \
            ac[6] = (short)bhi16(e1.z); ac[7] = (short)bhi16(e1.w);              \
            c1 = __builtin_amdgcn_mfma_f32_16x16x32_bf16(ac, WcB[c], c1, 0, 0, 0); \
            const float4 k0 = (c == 0) ? kq0 : kq2;                              \
            const float4 k1 = (c == 0) ? kq1 : kq3;                              \
            bf16x8 kf;                                                           \
            kf[0] = (short)bhi16(k0.x); kf[1] = (short)bhi16(k0.y);              \
            kf[2] = (short)bhi16(k0.z); kf[3] = (short)bhi16(k0.w);              \
            kf[4] = (short)bhi16(k1.x); kf[5] = (short)bhi16(k1.y);              \
            kf[6] = (short)bhi16(k1.z); kf[7] = (short)bhi16(k1.w);              \
            c2 = __builtin_amdgcn_mfma_f32_16x16x32_bf16(kf, QdB[c], c2, 0, 0, 0); \
        }                                                                        \
        if (m16 < 8) {                                                           \
            _Pragma("unroll")                                                    \
            for (int r = 0; r < 4; ++r) {                                        \
                const float E_ = fminf(fmaxf(c2[r] * SCALE, -5.f), 5.f) + c1[r]; \
                dn += __expf(E_ - SMAX);                                         \
                E_lds[w][(s) * 16 + a2 * 4 + r][m16] = E_;                       \
            }                                                                    \
        } else {                                                                 \
            _Pragma("unroll")                                                    \
            for (int r = 0; r < 4; ++r) gs += 1.f / (1.f + __expf(-c1[r]));      \
        } } while (0)

#define FLUSH(c) do {                                                            \
        f32x4 r0_ = *(const f32x4*)&E_lds[w][(c) * 64 + (l >> 1)][(l & 1) * 4];  \
        f32x4 r1_ = *(const f32x4*)&E_lds[w][(c) * 64 + 32 + (l >> 1)][(l & 1) * 4]; \
        float* dst_ = eob + (size_t)(rowbase + (c) * 64) * 8;                    \
        *(f32x4*)(dst_ + l * 4) = r0_;                                           \
        *(f32x4*)(dst_ + 256 + l * 4) = r1_;                                     \
    } while (0)

    STAGE(0);
    SLAB(0, 8); SLAB(1, 8); SLAB(2, 8); SLAB(3, 8);
    SLAB(4, 8); SLAB(5, 8); SLAB(6, 8); SLAB(7, 4);
    FLUSH(0); FLUSH(1);      // _E stash -> e_out row head; drains under PV

    // ---- reduce dn/gs across a2-groups (lanes share m16) ----
    dn += __shfl_xor(dn, 16, 64); dn += __shfl_xor(dn, 32, 64);
    gs += __shfl_xor(gs, 16, 64); gs += __shfl_xor(gs, 32, 64);
    if (a2 == 0 && m16 < 8) wdn[w][m16] = dn;
    if (a2 == 0 && m16 >= 8) wgs[w][m16 - 8] = gs;

    // ---- PV over own-wave rows: V line-coalesced, L2-hot ----
    {
        const int k = l & 7, hh = (l >> 3) & 7;
        const float* vb = qkv + (size_t)(b * NN + rowbase) * 192 + 128 + hh * 8 + k;
        float acc = 0.f;
#pragma unroll 8
        for (int i = 0; i < 128; ++i) {
            const float p = __expf(E_lds[w][i][hh] - SMAX);
            acc = fmaf(p, vb[(size_t)i * 192], acc);
        }
        red[t] = acc;
    }
    __syncthreads();
    if (t < 64) {
        const int hh = t >> 3;
        const float den = wdn[0][hh] + wdn[1][hh] + wdn[2][hh] + wdn[3][hh];
        const float gsum = wgs[0][hh] + wgs[1][hh] + wgs[2][hh] + wgs[3][hh];
        vfin[t] = (red[t] + red[64 + t] + red[128 + t] + red[192 + t]) * (1.f / den) * log1pf(gsum);
    }
    __syncthreads();
    {
        float acc = 0.f;
#pragma unroll
        for (int i = w * 16; i < w * 16 + 16; ++i)
            acc = fmaf(vfin[i], On[i * 64 + l], acc);
        red[t] = acc;
    }
    __syncthreads();
    if (t < 64)
        n_out[(size_t)bn * 64 + t] = red[t] + red[64 + t] + red[128 + t] + red[192 + t];

#undef STAGE
#undef SLAB
#undef FLUSH
}

// ---------------- K3: e_out = _E @ Oe (pure streaming, r3/r9-proven) -------
__global__ __launch_bounds__(256) void edge_out_stream(
    const float* __restrict__ Oe,   // (8,64)
    float* __restrict__ e_out)      // (B,N,N,64); row head holds the _E stash
{
    __shared__ float Es[NN * 8];    // 16 KB
    const int t = threadIdx.x;
    const int w = t >> 6;
    const int l = t & 63;
    const int bn = blockIdx.x;
    float* erow = e_out + (size_t)bn * 32768;

    {   // stash -> LDS (coalesced)
        const float4* src = reinterpret_cast<const float4*>(erow);
        float4* dst = reinterpret_cast<float4*>(Es);
#pragma unroll
        for (int i = 0; i < 4; ++i) dst[t + 256 * i] = src[t + 256 * i];
    }
    __syncthreads();

    const int j4 = l & 15, mr = l >> 4;
    float oc[8][4];
#pragma unroll
    for (int h = 0; h < 8; ++h) {
        const float4 v = reinterpret_cast<const float4*>(Oe + h * 64 + j4 * 4)[0];
        oc[h][0] = v.x; oc[h][1] = v.y; oc[h][2] = v.z; oc[h][3] = v.w;
    }
#pragma unroll 4
    for (int p = 0; p < 32; ++p) {
        const int m = w * 128 + p * 4 + mr;
        const float* er = Es + m * 8;
        const float4 ra = reinterpret_cast<const float4*>(er)[0];
        const float4 rb = reinterpret_cast<const float4*>(er)[1];
        float o0 = ra.x * oc[0][0], o1 = ra.x * oc[0][1], o2 = ra.x * oc[0][2], o3 = ra.x * oc[0][3];
        o0 = fmaf(ra.y, oc[1][0], o0); o1 = fmaf(ra.y, oc[1][1], o1); o2 = fmaf(ra.y, oc[1][2], o2); o3 = fmaf(ra.y, oc[1][3], o3);
        o0 = fmaf(ra.z, oc[2][0], o0); o1 = fmaf(ra.z, oc[2][1], o1); o2 = fmaf(ra.z, oc[2][2], o2); o3 = fmaf(ra.z, oc[2][3], o3);
        o0 = fmaf(ra.w, oc[3][0], o0); o1 = fmaf(ra.w, oc[3][1], o1); o2 = fmaf(ra.w, oc[3][2], o2); o3 = fmaf(ra.w, oc[3][3], o3);
        o0 = fmaf(rb.x, oc[4][0], o0); o1 = fmaf(rb.x, oc[4][1], o1); o2 = fmaf(rb.x, oc[4][2], o2); o3 = fmaf(rb.x, oc[4][3], o3);
        o0 = fmaf(rb.y, oc[5][0], o0); o1 = fmaf(rb.y, oc[5][1], o1); o2 = fmaf(rb.y, oc[5][2], o2); o3 = fmaf(rb.y, oc[5][3], o3);
        o0 = fmaf(rb.z, oc[6][0], o0); o1 = fmaf(rb.z, oc[6][1], o1); o2 = fmaf(rb.z, oc[6][2], o2); o3 = fmaf(rb.z, oc[6][3], o3);
        o0 = fmaf(rb.w, oc[7][0], o0); o1 = fmaf(rb.w, oc[7][1], o1); o2 = fmaf(rb.w, oc[7][2], o2); o3 = fmaf(rb.w, oc[7][3], o3);
        reinterpret_cast<float4*>(erow + (size_t)m * 64 + j4 * 4)[0] = make_float4(o0, o1, o2, o3);
    }
}

extern "C" void kernel_launch(void* const* d_in, const int* in_sizes, int n_in,
                              void* d_out, int out_size, void* d_ws, size_t ws_size,
                              hipStream_t stream) {
    const float* n_in_p = (const float*)d_in[0];
    const float* e_p    = (const float*)d_in[1];
    const float* Wqkv   = (const float*)d_in[2];
    const float* On     = (const float*)d_in[3];
    const float* Wg     = (const float*)d_in[4];
    const float* We     = (const float*)d_in[5];
    const float* Oe     = (const float*)d_in[6];
    float* out = (float*)d_out;
    float* n_out = out;                              // 4*512*64
    float* e_out = out + (size_t)4 * 512 * 64;       // 4*512*512*64
    float* qkv = (float*)d_ws;                       // 4*512*192 floats

    hipLaunchKernelGGL(qkv_proj, dim3(4 * NN), dim3(64), 0, stream, n_in_p, Wqkv, qkv);
    hipLaunchKernelGGL(edge_mfma2, dim3(4 * NN), dim3(256), 0, stream,
                       e_p, qkv, We, Wg, On, n_out, e_out);
    hipLaunchKernelGGL(edge_out_stream, dim3(4 * NN), dim3(256), 0, stream,
                       Oe, e_out);
}

// Round 11
// 188.607 us; speedup vs baseline: 1.4442x; 1.1098x over previous
//
#include <hip/hip_runtime.h>

#define NN 512
#define SCALE 0.35355339059327373f  /* dk^-0.5, dk=8 */
#define SMAX 6.0f                   /* fixed softmax shift (exact ratios) */

typedef short bf16x8 __attribute__((ext_vector_type(8)));
typedef float f32x4 __attribute__((ext_vector_type(4)));

__device__ __forceinline__ unsigned short bhi16(float x) {
    return (unsigned short)(__float_as_uint(x) >> 16);
}
__device__ __forceinline__ float btrunc(float x) {
    return __uint_as_float(__float_as_uint(x) & 0xFFFF0000u);
}
__device__ __forceinline__ unsigned short blo16(float x) {
    return (unsigned short)(__float_as_uint(x - btrunc(x)) >> 16);
}

// ---------------- K1: QKV projection ----------------
__global__ __launch_bounds__(64) void qkv_proj(const float* __restrict__ nin,
                                               const float* __restrict__ Wqkv,
                                               float* __restrict__ qkv) {
    const int r = blockIdx.x;
    const int j = threadIdx.x;
    const float* nr = nin + (size_t)r * 64;
    float a0 = 0.f, a1 = 0.f, a2 = 0.f;
#pragma unroll
    for (int d = 0; d < 64; ++d) {
        const float nv = nr[d];
        const float* wr = Wqkv + d * 192;
        a0 = fmaf(nv, wr[j], a0);
        a1 = fmaf(nv, wr[64 + j], a1);
        a2 = fmaf(nv, wr[128 + j], a2);
    }
    float* o = qkv + (size_t)r * 192;
    o[j] = a0; o[64 + j] = a1; o[128 + j] = a2;
}

__device__ __forceinline__ void gload16(const float* g, float* l) {
    __builtin_amdgcn_global_load_lds(
        (const __attribute__((address_space(1))) unsigned int*)(g),
        (__attribute__((address_space(3))) unsigned int*)(l), 16, 0, 0);
}
#define WAITV(N) asm volatile("s_waitcnt vmcnt(" #N ")" ::: "memory")
#define BARRIER() __builtin_amdgcn_s_barrier()
#define SBAR() __builtin_amdgcn_sched_barrier(0)

// ---------------- K2: fully fused (scores MFMA + e_out + PV + n_out) -------
// r10 structure, + e_out epilogue from E_lds (stash & K3 eliminated).
__global__ __launch_bounds__(256, 3) void edge_mfma3(
    const float* __restrict__ e,
    const float* __restrict__ qkv,
    const float* __restrict__ We,   // (64,8)
    const float* __restrict__ Wg,   // (64,8)
    const float* __restrict__ Oe,   // (8,64)
    const float* __restrict__ On,   // (64,64)
    float* __restrict__ n_out,
    float* __restrict__ e_out)
{
    __shared__ float ebuf[4][2][16][64];  // per-wave slab dbuf (32 KB)
    __shared__ float E_lds[4][128][8];    // per-wave E scores (16 KB)
    __shared__ float red[256];
    __shared__ float wdn[4][8], wgs[4][8];
    __shared__ float vfin[64];

    const int t = threadIdx.x, w = t >> 6, l = t & 63;
    const int a2 = l >> 4;      // k-block / D row-group
    const int m16 = l & 15;     // A-row / B-col / D-col
    const int bid = blockIdx.x;
    const int bn = (bid & 7) * 256 + (bid >> 3);   // XCD-chunked swizzle
    const int b = bn >> 9;
    const int rowbase = w * 128;
    const float* __restrict__ Q = qkv + (size_t)bn * 192;
    const float* __restrict__ ebase = e + (size_t)bn * 32768;
    float* __restrict__ eob = e_out + (size_t)bn * 32768;

    // ---- prologue: persistent B-fragments ----
    bf16x8 WfB[4], WcB[2], QdB[2];
#pragma unroll
    for (int blk = 0; blk < 4; ++blk) {
#pragma unroll
        for (int jj = 0; jj < 4; ++jj) {
            const int d = blk * 16 + a2 * 4 + jj;
            const float wv = (m16 < 8) ? We[d * 8 + m16] : Wg[d * 8 + m16 - 8];
            const short h = (short)bhi16(wv);
            WfB[blk][2 * jj] = h;          // A pairs (e_hi, e_lo) x same W_hi
            WfB[blk][2 * jj + 1] = h;
        }
    }
#pragma unroll
    for (int c = 0; c < 2; ++c) {
        const int head = c * 4 + a2;       // = d>>3 for this lane's k-slots
#pragma unroll
        for (int j = 0; j < 8; ++j) {
            const int d = c * 32 + a2 * 8 + j;
            const float wv = (m16 < 8) ? We[d * 8 + m16] : Wg[d * 8 + m16 - 8];
            WcB[c][j] = (short)blo16(wv);
            QdB[c][j] = (m16 == head) ? (short)bhi16(Q[d]) : (short)0;
        }
    }
    float dn = 0.f, gs = 0.f;
    SBAR();

#define STAGE(s) do {                                                            \
        _Pragma("unroll")                                                        \
        for (int i_ = 0; i_ < 4; ++i_) {                                         \
            const int lrow_ = i_ * 4 + (l >> 4);                                 \
            gload16(ebase + (size_t)(rowbase + (s) * 16 + lrow_) * 64            \
                        + (((l & 15) ^ lrow_) * 4),                              \
                    &ebuf[w][(s) & 1][i_ * 4][0]);                               \
        } } while (0)

#define SLAB(s, WN) do {                                                         \
        float4 kq0, kq1, kq2, kq3;                                               \
        { const float* kp_ = qkv + (size_t)(b * NN + rowbase + (s) * 16 + m16) * 192 \
                             + 64 + a2 * 8;                                      \
          kq0 = *(const float4*)(kp_);      kq1 = *(const float4*)(kp_ + 4);     \
          kq2 = *(const float4*)(kp_ + 32); kq3 = *(const float4*)(kp_ + 36); }  \
        SBAR();                                                                  \
        if ((s) < 7) STAGE((s) + 1);                                             \
        SBAR(); BARRIER(); WAITV(WN); SBAR();                                    \
        f32x4 c1 = {0.f, 0.f, 0.f, 0.f}, c2 = {0.f, 0.f, 0.f, 0.f};             \
        _Pragma("unroll")                                                        \
        for (int blk = 0; blk < 4; ++blk) {                                      \
            const float4 ev = *(const float4*)&ebuf[w][(s) & 1][m16]             \
                                  [(((blk * 4 + a2) ^ m16) * 4)];                \
            bf16x8 af;                                                           \
            af[0] = (short)bhi16(ev.x); af[1] = (short)blo16(ev.x);              \
            af[2] = (short)bhi16(ev.y); af[3] = (short)blo16(ev.y);              \
            af[4] = (short)bhi16(ev.z); af[5] = (short)blo16(ev.z);              \
            af[6] = (short)bhi16(ev.w); af[7] = (short)blo16(ev.w);              \
            c1 = __builtin_amdgcn_mfma_f32_16x16x32_bf16(af, WfB[blk], c1, 0, 0, 0); \
        }                                                                        \
        _Pragma("unroll")                                                        \
        for (int c = 0; c < 2; ++c) {                                            \
            const int g0 = c * 8 + a2 * 2;                                       \
            const float4 e0 = *(const float4*)&ebuf[w][(s) & 1][m16][((g0 ^ m16) * 4)]; \
            const float4 e1 = *(const float4*)&ebuf[w][(s) & 1][m16][(((g0 + 1) ^ m16) * 4)]; \
            bf16x8 ac;                                                           \
            ac[0] = (short)bhi16(e0.x); ac[1] = (short)bhi16(e0.y);              \
            ac[2] = (short)bhi16(e0.z); ac[3] = (short)bhi16(e0.w);              \
            ac[4] = (short)bhi16(e1.x); ac[5] = (short)bhi16(e1.y);              \
            ac[6] = (short)bhi16(e1.z); ac[7] = (short)bhi16(e1.w);              \
            c1 = __builtin_amdgcn_mfma_f32_16x16x32_bf16(ac, WcB[c], c1, 0, 0, 0); \
            const float4 k0 = (c == 0) ? kq0 : kq2;                              \
            const float4 k1 = (c == 0) ? kq1 : kq3;                              \
            bf16x8 kf;                                                           \
            kf[0] = (short)bhi16(k0.x); kf[1] = (short)bhi16(k0.y);              \
            kf[2] = (short)bhi16(k0.z); kf[3] = (short)bhi16(k0.w);              \
            kf[4] = (short)bhi16(k1.x); kf[5] = (short)bhi16(k1.y);              \
            kf[6] = (short)bhi16(k1.z); kf[7] = (short)bhi16(k1.w);              \
            c2 = __builtin_amdgcn_mfma_f32_16x16x32_bf16(kf, QdB[c], c2, 0, 0, 0); \
        }                                                                        \
        if (m16 < 8) {                                                           \
            _Pragma("unroll")                                                    \
            for (int r = 0; r < 4; ++r) {                                        \
                const float E_ = fminf(fmaxf(c2[r] * SCALE, -5.f), 5.f) + c1[r]; \
                dn += __expf(E_ - SMAX);                                         \
                E_lds[w][(s) * 16 + a2 * 4 + r][m16] = E_;                       \
            }                                                                    \
        } else {                                                                 \
            _Pragma("unroll")                                                    \
            for (int r = 0; r < 4; ++r) gs += 1.f / (1.f + __expf(-c1[r]));      \
        } } while (0)

    STAGE(0);
    SLAB(0, 8); SLAB(1, 8); SLAB(2, 8); SLAB(3, 8);
    SLAB(4, 8); SLAB(5, 8); SLAB(6, 8); SLAB(7, 0);

    // ---- e_out epilogue straight from E_lds (own-wave rows; full-line stores)
    {
        const int j4 = l & 15, mr = l >> 4;
        float oc[8][4];
#pragma unroll
        for (int h = 0; h < 8; ++h) {
            const float4 v = reinterpret_cast<const float4*>(Oe + h * 64 + j4 * 4)[0];
            oc[h][0] = v.x; oc[h][1] = v.y; oc[h][2] = v.z; oc[h][3] = v.w;
        }
#pragma unroll 4
        for (int p = 0; p < 32; ++p) {
            const int mloc = p * 4 + mr;
            const float* er = &E_lds[w][mloc][0];
            const float4 ra = *reinterpret_cast<const float4*>(er);
            const float4 rb = *reinterpret_cast<const float4*>(er + 4);
            float o0 = ra.x * oc[0][0], o1 = ra.x * oc[0][1], o2 = ra.x * oc[0][2], o3 = ra.x * oc[0][3];
            o0 = fmaf(ra.y, oc[1][0], o0); o1 = fmaf(ra.y, oc[1][1], o1); o2 = fmaf(ra.y, oc[1][2], o2); o3 = fmaf(ra.y, oc[1][3], o3);
            o0 = fmaf(ra.z, oc[2][0], o0); o1 = fmaf(ra.z, oc[2][1], o1); o2 = fmaf(ra.z, oc[2][2], o2); o3 = fmaf(ra.z, oc[2][3], o3);
            o0 = fmaf(ra.w, oc[3][0], o0); o1 = fmaf(ra.w, oc[3][1], o1); o2 = fmaf(ra.w, oc[3][2], o2); o3 = fmaf(ra.w, oc[3][3], o3);
            o0 = fmaf(rb.x, oc[4][0], o0); o1 = fmaf(rb.x, oc[4][1], o1); o2 = fmaf(rb.x, oc[4][2], o2); o3 = fmaf(rb.x, oc[4][3], o3);
            o0 = fmaf(rb.y, oc[5][0], o0); o1 = fmaf(rb.y, oc[5][1], o1); o2 = fmaf(rb.y, oc[5][2], o2); o3 = fmaf(rb.y, oc[5][3], o3);
            o0 = fmaf(rb.z, oc[6][0], o0); o1 = fmaf(rb.z, oc[6][1], o1); o2 = fmaf(rb.z, oc[6][2], o2); o3 = fmaf(rb.z, oc[6][3], o3);
            o0 = fmaf(rb.w, oc[7][0], o0); o1 = fmaf(rb.w, oc[7][1], o1); o2 = fmaf(rb.w, oc[7][2], o2); o3 = fmaf(rb.w, oc[7][3], o3);
            reinterpret_cast<float4*>(eob + (size_t)(rowbase + mloc) * 64 + j4 * 4)[0]
                = make_float4(o0, o1, o2, o3);
        }
    }

    // ---- reduce dn/gs across a2-groups (lanes share m16) ----
    dn += __shfl_xor(dn, 16, 64); dn += __shfl_xor(dn, 32, 64);
    gs += __shfl_xor(gs, 16, 64); gs += __shfl_xor(gs, 32, 64);
    if (a2 == 0 && m16 < 8) wdn[w][m16] = dn;
    if (a2 == 0 && m16 >= 8) wgs[w][m16 - 8] = gs;

    // ---- PV over own-wave rows: V line-coalesced, L2-hot ----
    {
        const int k = l & 7, hh = (l >> 3) & 7;
        const float* vb = qkv + (size_t)(b * NN + rowbase) * 192 + 128 + hh * 8 + k;
        float acc = 0.f;
#pragma unroll 8
        for (int i = 0; i < 128; ++i) {
            const float p = __expf(E_lds[w][i][hh] - SMAX);
            acc = fmaf(p, vb[(size_t)i * 192], acc);
        }
        red[t] = acc;
    }
    __syncthreads();
    if (t < 64) {
        const int hh = t >> 3;
        const float den = wdn[0][hh] + wdn[1][hh] + wdn[2][hh] + wdn[3][hh];
        const float gsum = wgs[0][hh] + wgs[1][hh] + wgs[2][hh] + wgs[3][hh];
        vfin[t] = (red[t] + red[64 + t] + red[128 + t] + red[192 + t]) * (1.f / den) * log1pf(gsum);
    }
    __syncthreads();
    {
        float acc = 0.f;
#pragma unroll
        for (int i = w * 16; i < w * 16 + 16; ++i)
            acc = fmaf(vfin[i], On[i * 64 + l], acc);
        red[t] = acc;
    }
    __syncthreads();
    if (t < 64)
        n_out[(size_t)bn * 64 + t] = red[t] + red[64 + t] + red[128 + t] + red[192 + t];

#undef STAGE
#undef SLAB
}

extern "C" void kernel_launch(void* const* d_in, const int* in_sizes, int n_in,
                              void* d_out, int out_size, void* d_ws, size_t ws_size,
                              hipStream_t stream) {
    const float* n_in_p = (const float*)d_in[0];
    const float* e_p    = (const float*)d_in[1];
    const float* Wqkv   = (const float*)d_in[2];
    const float* On     = (const float*)d_in[3];
    const float* Wg     = (const float*)d_in[4];
    const float* We     = (const float*)d_in[5];
    const float* Oe     = (const float*)d_in[6];
    float* out = (float*)d_out;
    float* n_out = out;                              // 4*512*64
    float* e_out = out + (size_t)4 * 512 * 64;       // 4*512*512*64
    float* qkv = (float*)d_ws;                       // 4*512*192 floats

    hipLaunchKernelGGL(qkv_proj, dim3(4 * NN), dim3(64), 0, stream, n_in_p, Wqkv, qkv);
    hipLaunchKernelGGL(edge_mfma3, dim3(4 * NN), dim3(256), 0, stream,
                       e_p, qkv, We, Wg, Oe, On, n_out, e_out);
}